// Round 19
// baseline (443.778 us; speedup 1.0000x reference)
//
#include <hip/hip_runtime.h>
#include <hip/hip_bf16.h>
#include <math.h>

#define Bsz 1024
#define Nn  11
#define Ff  512
#define Zi  10
#define G3  1536

#define PEC 65    // link Eb plane stride (64 rows + 1 pad chunk)

typedef __attribute__((ext_vector_type(8))) short bfrag;
typedef __attribute__((ext_vector_type(4))) float f32x4;

__device__ __forceinline__ unsigned f2bf(float f) {
    __hip_bfloat16 h = __float2bfloat16(f);
    return (unsigned)*reinterpret_cast<unsigned short*>(&h);
}
__device__ __forceinline__ float bf2f(unsigned short u) {
    union { unsigned int i; float f; } v;
    v.i = ((unsigned int)u) << 16;
    return v.f;
}
__device__ __forceinline__ uint4 pack8(float v0, float v1, float v2, float v3,
                                       float v4, float v5, float v6, float v7) {
    uint4 pk;
    pk.x = f2bf(v0) | (f2bf(v1) << 16);
    pk.y = f2bf(v2) | (f2bf(v3) << 16);
    pk.z = f2bf(v4) | (f2bf(v5) << 16);
    pk.w = f2bf(v6) | (f2bf(v7) << 16);
    return pk;
}
__device__ __forceinline__ void pair_decode(int mode, int p, int& pi, int& pj) {
    if (mode == 0) { int r = p, i = 0; while (r >= Nn - i) { r -= Nn - i; ++i; } pi = i; pj = i + r; }
    else { pi = p; pj = Zi; }
}
// async global->LDS, 16B/lane; dst must be wave-uniform base (+lane*16 by HW)
__device__ __forceinline__ void gl_lds16(const void* src, void* dst) {
    __builtin_amdgcn_global_load_lds((const __attribute__((address_space(1))) void*)src,
                                     (__attribute__((address_space(3))) void*)dst, 16, 0, 0);
}

// ---------------------------------------------------------------------------
// init: col fp32 AND colbf (packed bf16, kq-plane-major per 64-row block)
// ---------------------------------------------------------------------------
__global__ void init_col2_kernel(const float* __restrict__ nf, float* __restrict__ col,
                                 unsigned short* __restrict__ colbf) {
    int idx = blockIdx.x * 256 + threadIdx.x;   // Bsz*64
    int b = idx >> 6, kq = idx & 63;
    const float* s = nf + (b * Nn + Zi) * Ff + kq * 8;
    float4 a = *(const float4*)s, c = *(const float4*)(s + 4);
    *(float4*)(col + b * Ff + kq * 8)     = a;
    *(float4*)(col + b * Ff + kq * 8 + 4) = c;
    long long dc = (((long long)(b >> 6) * 64 + kq) << 6) + (b & 63);
    *(uint4*)((char*)colbf + dc * 16) = pack8(a.x, a.y, a.z, a.w, c.x, c.y, c.z, c.w);
}

// ---------------------------------------------------------------------------
// pack fp32 W[g][k] -> bf16 kq-plane-major chunks; goff = global row offset
// ---------------------------------------------------------------------------
__global__ void pack_w_kernel(const float* __restrict__ src,
                              unsigned short* __restrict__ dst, int lgBW, int goff) {
    int idx = blockIdx.x * 256 + threadIdx.x;
    int gl_ = idx >> 6, kq = idx & 63;
    int g = gl_ + goff;
    int nb = g >> lgBW, gg = g & ((1 << lgBW) - 1);
    const float* s = src + gl_ * Ff + kq * 8;
    float4 a = *(const float4*)s, b = *(const float4*)(s + 4);
    uint4 pk = pack8(a.x, a.y, a.z, a.w, b.x, b.y, b.z, b.w);
    long long dc = (((long long)(nb << 6) + kq) << lgBW) + gg;
    *(uint4*)((char*)dst + dc * 16) = pk;
}

// ---------------------------------------------------------------------------
// Fused link MLP (R15-exact). Block = 64 rows x 512 cols, 512 thr / 8 waves;
// wave tile 64x64 = 4x4 of mfma_f32_16x16x32_bf16. E resident in LDS; W
// direct global->VGPR ping-pong. 3 barriers total. LDS 68.6 KB.
// ---------------------------------------------------------------------------
__global__ __launch_bounds__(512, 2) void link_kernel(
    const float* __restrict__ nf, const float* __restrict__ colp,
    const unsigned short* __restrict__ W1p, const float* __restrict__ b1,
    const unsigned short* __restrict__ W2p, const float* __restrict__ b2,
    const float* __restrict__ w_out, const float* __restrict__ b_out,
    float* __restrict__ adj, int mode)
{
    __shared__ __align__(16) char Eb[64 * PEC * 16];     // 66,560 B
    __shared__ float Pl[8][64];                          //  2,048 B

    const int tid = threadIdx.x;
    const int pr  = blockIdx.x >> 4;
    const int bc  = blockIdx.x & 15;
    int pi, pj; pair_decode(mode, pr, pi, pj);

    const int wid  = tid >> 6;
    const int l    = tid & 63;
    const int lr16 = l & 15;
    const int kq4  = l >> 4;

    const bfrag* W1c = (const bfrag*)W1p;
    const bfrag* W2c = (const bfrag*)W2p;
    const int wcb = wid * 64 + lr16;

    bfrag wb0[4], wb1[4];
    auto loadW = [&](int gs, bfrag* dst) {   // gs = global step 0..31
        const bfrag* Wc = (gs >= 16) ? W2c : W1c;
        const int base = ((gs & 15) * 4 + kq4) * 512 + wcb;
#pragma unroll
        for (int nt = 0; nt < 4; ++nt) dst[nt] = Wc[base + nt * 16];
    };

    loadW(0, wb0);

    // ---- E build: row = tid>>3 (64 rows), kc = tid&7 covers 64 k each ----
    {
        const int row = tid >> 3;
        const int kc  = tid & 7;
        const int b   = bc * 64 + row;
        const float* xi = (pi == Zi) ? (colp + b * Ff) : (nf + (b * Nn + pi) * Ff);
        const float* xj = (pj == Zi) ? (colp + b * Ff) : (nf + (b * Nn + pj) * Ff);
#pragma unroll
        for (int i = 0; i < 8; ++i) {
            const int k0 = kc * 64 + i * 8;
            const int plane = k0 >> 3;
            float4 u0 = *(const float4*)(xi + k0), u1 = *(const float4*)(xi + k0 + 4);
            float4 v0 = *(const float4*)(xj + k0), v1 = *(const float4*)(xj + k0 + 4);
            *(uint4*)(&Eb[(plane * PEC + row) * 16]) =
                pack8(u0.x*v0.x, u0.y*v0.y, u0.z*v0.z, u0.w*v0.w,
                      u1.x*v1.x, u1.y*v1.y, u1.z*v1.z, u1.w*v1.w);
        }
    }
    __syncthreads();    // E published

    f32x4 acc[4][4];
#pragma unroll
    for (int mt = 0; mt < 4; ++mt)
#pragma unroll
        for (int nt = 0; nt < 4; ++nt) acc[mt][nt] = (f32x4){0.f, 0.f, 0.f, 0.f};

#define DO_STEP(S, WB) { \
    const int ebase = ((S) & 15) * 4 + kq4; \
    bfrag a0 = *(const bfrag*)(&Eb[(ebase * PEC +      lr16) * 16]); \
    bfrag a1 = *(const bfrag*)(&Eb[(ebase * PEC + 16 + lr16) * 16]); \
    bfrag a2 = *(const bfrag*)(&Eb[(ebase * PEC + 32 + lr16) * 16]); \
    bfrag a3 = *(const bfrag*)(&Eb[(ebase * PEC + 48 + lr16) * 16]); \
    acc[0][0] = __builtin_amdgcn_mfma_f32_16x16x32_bf16(a0, WB[0], acc[0][0], 0, 0, 0); \
    acc[0][1] = __builtin_amdgcn_mfma_f32_16x16x32_bf16(a0, WB[1], acc[0][1], 0, 0, 0); \
    acc[0][2] = __builtin_amdgcn_mfma_f32_16x16x32_bf16(a0, WB[2], acc[0][2], 0, 0, 0); \
    acc[0][3] = __builtin_amdgcn_mfma_f32_16x16x32_bf16(a0, WB[3], acc[0][3], 0, 0, 0); \
    acc[1][0] = __builtin_amdgcn_mfma_f32_16x16x32_bf16(a1, WB[0], acc[1][0], 0, 0, 0); \
    acc[1][1] = __builtin_amdgcn_mfma_f32_16x16x32_bf16(a1, WB[1], acc[1][1], 0, 0, 0); \
    acc[1][2] = __builtin_amdgcn_mfma_f32_16x16x32_bf16(a1, WB[2], acc[1][2], 0, 0, 0); \
    acc[1][3] = __builtin_amdgcn_mfma_f32_16x16x32_bf16(a1, WB[3], acc[1][3], 0, 0, 0); \
    acc[2][0] = __builtin_amdgcn_mfma_f32_16x16x32_bf16(a2, WB[0], acc[2][0], 0, 0, 0); \
    acc[2][1] = __builtin_amdgcn_mfma_f32_16x16x32_bf16(a2, WB[1], acc[2][1], 0, 0, 0); \
    acc[2][2] = __builtin_amdgcn_mfma_f32_16x16x32_bf16(a2, WB[2], acc[2][2], 0, 0, 0); \
    acc[2][3] = __builtin_amdgcn_mfma_f32_16x16x32_bf16(a2, WB[3], acc[2][3], 0, 0, 0); \
    acc[3][0] = __builtin_amdgcn_mfma_f32_16x16x32_bf16(a3, WB[0], acc[3][0], 0, 0, 0); \
    acc[3][1] = __builtin_amdgcn_mfma_f32_16x16x32_bf16(a3, WB[1], acc[3][1], 0, 0, 0); \
    acc[3][2] = __builtin_amdgcn_mfma_f32_16x16x32_bf16(a3, WB[2], acc[3][2], 0, 0, 0); \
    acc[3][3] = __builtin_amdgcn_mfma_f32_16x16x32_bf16(a3, WB[3], acc[3][3], 0, 0, 0); }

    // ---- layer 1: steps 0..15 (no barriers) ----
#pragma unroll 1
    for (int s2 = 0; s2 < 8; ++s2) {
        const int s = 2 * s2;
        loadW(s + 1, wb1);
        DO_STEP(s, wb0)
        loadW(s + 2, wb0);           // s2==7 -> slice 16 = W2 slice 0
        DO_STEP(s + 1, wb1)
    }

    // ---- layer boundary: h1 = relu(acc+b1) -> Eb in place ----
    __syncthreads();                 // all layer-1 E reads done
    {
#pragma unroll
        for (int nt = 0; nt < 4; ++nt) {
            const int c  = wid * 64 + nt * 16 + lr16;
            const float bv = b1[c];
#pragma unroll
            for (int mt = 0; mt < 4; ++mt)
#pragma unroll
                for (int reg = 0; reg < 4; ++reg) {
                    int row = mt * 16 + kq4 * 4 + reg;
                    float v = fmaxf(acc[mt][nt][reg] + bv, 0.f);
                    *(unsigned short*)(&Eb[((c >> 3) * PEC + row) * 16 + (c & 7) * 2]) =
                        (unsigned short)f2bf(v);
                }
        }
#pragma unroll
        for (int mt = 0; mt < 4; ++mt)
#pragma unroll
            for (int nt = 0; nt < 4; ++nt) acc[mt][nt] = (f32x4){0.f, 0.f, 0.f, 0.f};
    }
    __syncthreads();                 // h1 published

    // ---- layer 2: steps 16..31 (no barriers) ----
#pragma unroll 1
    for (int s2 = 0; s2 < 8; ++s2) {
        const int s = 16 + 2 * s2;
        loadW(s + 1, wb1);
        DO_STEP(s, wb0)
        if (s2 < 7) loadW(s + 2, wb0);
        DO_STEP(s + 1, wb1)
    }
#undef DO_STEP

    // ---- fused layer-3: rowsum of relu(acc+b2)*w_out ----
    {
        float rs[4][4];
#pragma unroll
        for (int mt = 0; mt < 4; ++mt)
#pragma unroll
            for (int reg = 0; reg < 4; ++reg) rs[mt][reg] = 0.f;
#pragma unroll
        for (int nt = 0; nt < 4; ++nt) {
            const int c  = wid * 64 + nt * 16 + lr16;
            const float bv = b2[c];
            const float wv = w_out[c];
#pragma unroll
            for (int mt = 0; mt < 4; ++mt)
#pragma unroll
                for (int reg = 0; reg < 4; ++reg)
                    rs[mt][reg] += fmaxf(acc[mt][nt][reg] + bv, 0.f) * wv;
        }
#pragma unroll
        for (int off = 1; off < 16; off <<= 1)
#pragma unroll
            for (int mt = 0; mt < 4; ++mt)
#pragma unroll
                for (int reg = 0; reg < 4; ++reg)
                    rs[mt][reg] += __shfl_xor(rs[mt][reg], off);
        if (lr16 == 0) {
#pragma unroll
            for (int mt = 0; mt < 4; ++mt)
#pragma unroll
                for (int reg = 0; reg < 4; ++reg) {
                    int row = mt * 16 + kq4 * 4 + reg;
                    Pl[wid][row] = rs[mt][reg];
                }
        }
    }
    __syncthreads();
    if (tid < 64) {
        float v = b_out[0];
#pragma unroll
        for (int w = 0; w < 8; ++w) v += Pl[w][tid];
        int b = bc * 64 + tid;
        adj[b * (Nn * Nn) + pi * Nn + pj] = v;
        if (pi != pj) adj[b * (Nn * Nn) + pj * Nn + pi] = v;
    }
}

// ---------------------------------------------------------------------------
__global__ void softmax_az_kernel(const float* __restrict__ adj, float* __restrict__ a_z) {
    int b = blockIdx.x * 256 + threadIdx.x;
    if (b >= Bsz) return;
    const float* row = adj + b * (Nn * Nn) + Zi * Nn;
    float mx = row[0];
#pragma unroll
    for (int j = 1; j < Nn; ++j) mx = fmaxf(mx, row[j]);
    float e[Nn]; float s = 0.f;
#pragma unroll
    for (int j = 0; j < Nn; ++j) { e[j] = expf(row[j] - mx); s += e[j]; }
    float inv = 1.f / s;
#pragma unroll
    for (int j = 0; j < Nn; ++j) a_z[b * Nn + j] = e[j] * inv;
}

// ---------------------------------------------------------------------------
// mfixpack: m_fix[b,f] = sum_{j<10} az[j]*nf[b,j,f] -> packed bf16
// ---------------------------------------------------------------------------
__global__ void mfixpack_kernel(const float* __restrict__ nf, const float* __restrict__ a_z,
                                unsigned short* __restrict__ m_fixp) {
    int idx = blockIdx.x * 256 + threadIdx.x;   // Bsz*64
    int b = idx >> 6, kq = idx & 63;
    const float* az = a_z + b * Nn;
    const int f0 = kq * 8;
    float s0 = 0.f, s1 = 0.f, s2 = 0.f, s3 = 0.f, s4 = 0.f, s5 = 0.f, s6 = 0.f, s7 = 0.f;
#pragma unroll
    for (int j = 0; j < Nn - 1; ++j) {
        float aj = az[j];
        const float* p = nf + (b * Nn + j) * Ff + f0;
        float4 n0 = *(const float4*)p, n1 = *(const float4*)(p + 4);
        s0 += aj * n0.x; s1 += aj * n0.y; s2 += aj * n0.z; s3 += aj * n0.w;
        s4 += aj * n1.x; s5 += aj * n1.y; s6 += aj * n1.z; s7 += aj * n1.w;
    }
    long long dc = (((long long)(b >> 6) * 64 + kq) << 6) + (b & 63);
    *(uint4*)((char*)m_fixp + dc * 16) = pack8(s0, s1, s2, s3, s4, s5, s6, s7);
}

// ---------------------------------------------------------------------------
// Generic GEMM core (R15 gates structure): block 64 rows x 256 cols, 256 thr,
// 4 waves, wave tile 64x64. A staged once via gl_lds (linear 64KB planes);
// W direct global->VGPR ping-pong. Ends with acc[4][4] computed; kernels
// append their own epilogue AFTER the macro (no #pragma in macro args).
// ---------------------------------------------------------------------------
#define GEMM_CORE                                                              \
    __shared__ __align__(16) char Ab[64 * 64 * 16];                            \
    const int xb = blockIdx.x, bc = blockIdx.y, tid = threadIdx.x;             \
    const int nbase = xb * 256;                                                \
    const int wid  = tid >> 6;                                                 \
    const int l    = tid & 63;                                                 \
    const int lr16 = l & 15;                                                   \
    const int kq4  = l >> 4;                                                   \
    const bfrag* Wc = (const bfrag*)Wp;                                        \
    const int wcb = ((nbase >> 9) << 15) + (nbase & 511) + wid * 64 + lr16;    \
    bfrag wb0[4], wb1[4];                                                      \
    auto loadW = [&](int s, bfrag* dst) {                                      \
        if (s > 15) s = 15;                                                    \
        const int base = wcb + (s * 4 + kq4) * 512;                            \
        _Pragma("unroll")                                                      \
        for (int nt = 0; nt < 4; ++nt) dst[nt] = Wc[base + nt * 16];           \
    };                                                                         \
    loadW(0, wb0);                                                             \
    _Pragma("unroll")                                                          \
    for (int i = 0; i < 16; ++i) {                                             \
        int cb = i * 256 + wid * 64;                                           \
        gl_lds16(Ap + ((long long)bc * 4096 + cb + l) * 8, (char*)Ab + cb * 16); \
    }                                                                          \
    __syncthreads();                                                           \
    f32x4 acc[4][4];                                                           \
    _Pragma("unroll")                                                          \
    for (int mt = 0; mt < 4; ++mt)                                             \
        _Pragma("unroll")                                                      \
        for (int nt = 0; nt < 4; ++nt) acc[mt][nt] = (f32x4){0.f, 0.f, 0.f, 0.f}; \
    _Pragma("unroll 1")                                                        \
    for (int s2 = 0; s2 < 8; ++s2) {                                           \
        const int s = 2 * s2;                                                  \
        loadW(s + 1, wb1);                                                     \
        { const int ebase = s * 4 + kq4;                                       \
          bfrag a0 = *(const bfrag*)(&Ab[(ebase * 64 +      lr16) * 16]);      \
          bfrag a1 = *(const bfrag*)(&Ab[(ebase * 64 + 16 + lr16) * 16]);      \
          bfrag a2 = *(const bfrag*)(&Ab[(ebase * 64 + 32 + lr16) * 16]);      \
          bfrag a3 = *(const bfrag*)(&Ab[(ebase * 64 + 48 + lr16) * 16]);      \
          _Pragma("unroll")                                                    \
          for (int nt = 0; nt < 4; ++nt) {                                     \
            acc[0][nt] = __builtin_amdgcn_mfma_f32_16x16x32_bf16(a0, wb0[nt], acc[0][nt], 0, 0, 0); \
            acc[1][nt] = __builtin_amdgcn_mfma_f32_16x16x32_bf16(a1, wb0[nt], acc[1][nt], 0, 0, 0); \
            acc[2][nt] = __builtin_amdgcn_mfma_f32_16x16x32_bf16(a2, wb0[nt], acc[2][nt], 0, 0, 0); \
            acc[3][nt] = __builtin_amdgcn_mfma_f32_16x16x32_bf16(a3, wb0[nt], acc[3][nt], 0, 0, 0); \
          } }                                                                  \
        loadW(s + 2, wb0);                                                     \
        { const int ebase = (s + 1) * 4 + kq4;                                 \
          bfrag a0 = *(const bfrag*)(&Ab[(ebase * 64 +      lr16) * 16]);      \
          bfrag a1 = *(const bfrag*)(&Ab[(ebase * 64 + 16 + lr16) * 16]);      \
          bfrag a2 = *(const bfrag*)(&Ab[(ebase * 64 + 32 + lr16) * 16]);      \
          bfrag a3 = *(const bfrag*)(&Ab[(ebase * 64 + 48 + lr16) * 16]);      \
          _Pragma("unroll")                                                    \
          for (int nt = 0; nt < 4; ++nt) {                                     \
            acc[0][nt] = __builtin_amdgcn_mfma_f32_16x16x32_bf16(a0, wb1[nt], acc[0][nt], 0, 0, 0); \
            acc[1][nt] = __builtin_amdgcn_mfma_f32_16x16x32_bf16(a1, wb1[nt], acc[1][nt], 0, 0, 0); \
            acc[2][nt] = __builtin_amdgcn_mfma_f32_16x16x32_bf16(a2, wb1[nt], acc[2][nt], 0, 0, 0); \
            acc[3][nt] = __builtin_amdgcn_mfma_f32_16x16x32_bf16(a3, wb1[nt], acc[3][nt], 0, 0, 0); \
          } }                                                                  \
    }

// gifix: out bf16 [row][1536]
__global__ __launch_bounds__(256, 2) void gifix_kernel(
    const unsigned short* __restrict__ Ap, const unsigned short* __restrict__ Wp,
    unsigned short* __restrict__ Cout)
{
    GEMM_CORE
#pragma unroll
    for (int nt = 0; nt < 4; ++nt) {
        const int c = nbase + wid * 64 + nt * 16 + lr16;
#pragma unroll
        for (int mt = 0; mt < 4; ++mt)
#pragma unroll
            for (int reg = 0; reg < 4; ++reg) {
                int row = mt * 16 + kq4 * 4 + reg;
                Cout[(bc * 64 + row) * G3 + c] = (unsigned short)f2bf(acc[mt][nt][reg]);
            }
    }
}

// gatescat: out fp32 [row][3072]
__global__ __launch_bounds__(256, 2) void gatescat_kernel(
    const unsigned short* __restrict__ Ap, const unsigned short* __restrict__ Wp,
    float* __restrict__ Cout)
{
    GEMM_CORE
#pragma unroll
    for (int nt = 0; nt < 4; ++nt) {
        const int c = nbase + wid * 64 + nt * 16 + lr16;
#pragma unroll
        for (int mt = 0; mt < 4; ++mt)
#pragma unroll
            for (int reg = 0; reg < 4; ++reg) {
                int row = mt * 16 + kq4 * 4 + reg;
                Cout[(bc * 64 + row) * 3072 + c] = acc[mt][nt][reg];
            }
    }
}

// ---------------------------------------------------------------------------
// gru2: gi = gifix + az10*u (u = C3[:, :1536]); gh = C3[:, 1536:];
// GRU pointwise; writes col fp32 + colbf packed. 8 f per thread.
// ---------------------------------------------------------------------------
__global__ void gru2_kernel(const unsigned short* __restrict__ gifixb,
                            const float* __restrict__ C3,
                            const float* __restrict__ a_z,
                            float* __restrict__ col,
                            unsigned short* __restrict__ colbf) {
    int idx = blockIdx.x * 256 + threadIdx.x;   // Bsz*64
    int b = idx >> 6, kq = idx & 63;
    const int f0 = kq * 8;
    const float az10 = a_z[b * Nn + Zi];
    const float* u  = C3 + (long long)b * 3072;
    const float* hh = u + G3;
    const unsigned short* gf = gifixb + (long long)b * G3;

    float o[8];
#pragma unroll
    for (int k = 0; k < 8; ++k) {
        int f = f0 + k;
        float ir = bf2f(gf[f])        + az10 * u[f];
        float iz = bf2f(gf[512 + f])  + az10 * u[512 + f];
        float in = bf2f(gf[1024 + f]) + az10 * u[1024 + f];
        float hr = hh[f], hz = hh[512 + f], hn = hh[1024 + f];
        float r = 1.f / (1.f + expf(-(ir + hr)));
        float z = 1.f / (1.f + expf(-(iz + hz)));
        float n = tanhf(in + r * hn);
        float h = col[b * Ff + f];
        o[k] = (1.f - z) * n + z * h;
    }
    *(float4*)(col + b * Ff + f0)     = (float4){o[0], o[1], o[2], o[3]};
    *(float4*)(col + b * Ff + f0 + 4) = (float4){o[4], o[5], o[6], o[7]};
    long long dc = (((long long)(b >> 6) * 64 + kq) << 6) + (b & 63);
    *(uint4*)((char*)colbf + dc * 16) = pack8(o[0], o[1], o[2], o[3], o[4], o[5], o[6], o[7]);
}

// ---------------------------------------------------------------------------
extern "C" void kernel_launch(void* const* d_in, const int* in_sizes, int n_in,
                              void* d_out, int out_size, void* d_ws, size_t ws_size,
                              hipStream_t stream) {
    const float* nf    = (const float*)d_in[0];
    const float* W1    = (const float*)d_in[1];
    const float* b1    = (const float*)d_in[2];
    const float* W2    = (const float*)d_in[3];
    const float* b2    = (const float*)d_in[4];
    const float* w_out = (const float*)d_in[5];
    const float* b_out = (const float*)d_in[6];
    const float* W_ih  = (const float*)d_in[7];
    const float* W_hh  = (const float*)d_in[8];

    float* adj = (float*)d_out;                 // (B, 11, 11)
    float* col = adj + Bsz * Nn * Nn;           // (B, 512)

    unsigned short* W1p    = (unsigned short*)d_ws;        // 512x512
    unsigned short* W2p    = W1p + Ff * Ff;                // 512x512
    unsigned short* Wcatp  = W2p + Ff * Ff;                // 3072x512 ([Wih;Whh])
    float* a_z             = (float*)(Wcatp + 2 * G3 * Ff);
    unsigned short* colbf  = (unsigned short*)(a_z + 16384);   // B*512 packed
    unsigned short* gifixb = colbf + Bsz * Ff;                 // B*1536 bf16
    float* C3              = (float*)(gifixb + (long long)Bsz * G3);  // B*3072 fp32
    unsigned short* m_fixp = (unsigned short*)C3;              // alias (time-disjoint)

    init_col2_kernel<<<(Bsz * 64) / 256, 256, 0, stream>>>(nf, col, colbf);
    pack_w_kernel<<<(Ff * 64) / 256, 256, 0, stream>>>(W1, W1p, 9, 0);
    pack_w_kernel<<<(Ff * 64) / 256, 256, 0, stream>>>(W2, W2p, 9, 0);
    pack_w_kernel<<<(G3 * 64) / 256, 256, 0, stream>>>(W_ih, Wcatp, 9, 0);
    pack_w_kernel<<<(G3 * 64) / 256, 256, 0, stream>>>(W_hh, Wcatp, 9, G3);

    for (int t = 0; t < 3; ++t) {
        const int mode   = (t == 0) ? 0 : 1;
        const int npairs = (t == 0) ? 66 : 11;

        link_kernel<<<npairs * 16, 512, 0, stream>>>(nf, col, W1p, b1, W2p, b2,
                                                     w_out, b_out, adj, mode);
        softmax_az_kernel<<<Bsz / 256, 256, 0, stream>>>(adj, a_z);
        mfixpack_kernel<<<(Bsz * 64) / 256, 256, 0, stream>>>(nf, a_z, m_fixp);
        gifix_kernel<<<dim3(6, 16), 256, 0, stream>>>(m_fixp, Wcatp, gifixb);

        for (int s = 0; s < 3; ++s) {
            gatescat_kernel<<<dim3(12, 16), 256, 0, stream>>>(colbf, Wcatp, C3);
            gru2_kernel<<<(Bsz * 64) / 256, 256, 0, stream>>>(gifixb, C3, a_z, col, colbf);
        }
    }
}

// Round 20
// 366.132 us; speedup vs baseline: 1.2121x; 1.2121x over previous
//
#include <hip/hip_runtime.h>
#include <hip/hip_bf16.h>
#include <math.h>

#define Bsz 1024
#define Nn  11
#define Ff  512
#define Zi  10
#define G3  1536

#define PEC 65    // link Eb plane stride (64 rows + 1 pad chunk)

typedef __attribute__((ext_vector_type(8))) short bfrag;
typedef __attribute__((ext_vector_type(4))) float f32x4;

__device__ __forceinline__ unsigned f2bf(float f) {
    __hip_bfloat16 h = __float2bfloat16(f);
    return (unsigned)*reinterpret_cast<unsigned short*>(&h);
}
__device__ __forceinline__ uint4 pack8(float v0, float v1, float v2, float v3,
                                       float v4, float v5, float v6, float v7) {
    uint4 pk;
    pk.x = f2bf(v0) | (f2bf(v1) << 16);
    pk.y = f2bf(v2) | (f2bf(v3) << 16);
    pk.z = f2bf(v4) | (f2bf(v5) << 16);
    pk.w = f2bf(v6) | (f2bf(v7) << 16);
    return pk;
}
__device__ __forceinline__ void pair_decode(int mode, int p, int& pi, int& pj) {
    if (mode == 0) { int r = p, i = 0; while (r >= Nn - i) { r -= Nn - i; ++i; } pi = i; pj = i + r; }
    else { pi = p; pj = Zi; }
}
// async global->LDS, 16B/lane; dst must be wave-uniform base (+lane*16 by HW)
__device__ __forceinline__ void gl_lds16(const void* src, void* dst) {
    __builtin_amdgcn_global_load_lds((const __attribute__((address_space(1))) void*)src,
                                     (__attribute__((address_space(3))) void*)dst, 16, 0, 0);
}

// ---------------------------------------------------------------------------
// init: col fp32 AND colbf (packed bf16, kq-plane-major per 64-row block)
// ---------------------------------------------------------------------------
__global__ void init_col2_kernel(const float* __restrict__ nf, float* __restrict__ col,
                                 unsigned short* __restrict__ colbf) {
    int idx = blockIdx.x * 256 + threadIdx.x;   // Bsz*64
    int b = idx >> 6, kq = idx & 63;
    const float* s = nf + (b * Nn + Zi) * Ff + kq * 8;
    float4 a = *(const float4*)s, c = *(const float4*)(s + 4);
    *(float4*)(col + b * Ff + kq * 8)     = a;
    *(float4*)(col + b * Ff + kq * 8 + 4) = c;
    long long dc = (((long long)(b >> 6) * 64 + kq) << 6) + (b & 63);
    *(uint4*)((char*)colbf + dc * 16) = pack8(a.x, a.y, a.z, a.w, c.x, c.y, c.z, c.w);
}

// ---------------------------------------------------------------------------
// pack fp32 W[g][k] -> bf16 kq-plane-major chunks (contiguous/coalescable)
// ---------------------------------------------------------------------------
__global__ void pack_w_kernel(const float* __restrict__ src,
                              unsigned short* __restrict__ dst, int lgBW) {
    int idx = blockIdx.x * 256 + threadIdx.x;   // total G*64 chunks
    int g = idx >> 6, kq = idx & 63;
    int nb = g >> lgBW, gl = g & ((1 << lgBW) - 1);
    const float* s = src + g * Ff + kq * 8;
    float4 a = *(const float4*)s, b = *(const float4*)(s + 4);
    uint4 pk = pack8(a.x, a.y, a.z, a.w, b.x, b.y, b.z, b.w);
    long long dc = (((long long)(nb << 6) + kq) << lgBW) + gl;
    *(uint4*)((char*)dst + dc * 16) = pk;
}

// ---------------------------------------------------------------------------
// Fused link MLP (R15-exact). Block = 64 rows x 512 cols, 512 thr / 8 waves;
// wave tile 64x64 = 4x4 of mfma_f32_16x16x32_bf16. E resident in LDS; W
// direct global->VGPR ping-pong. 3 barriers total. LDS 68.6 KB.
// ---------------------------------------------------------------------------
__global__ __launch_bounds__(512, 2) void link_kernel(
    const float* __restrict__ nf, const float* __restrict__ colp,
    const unsigned short* __restrict__ W1p, const float* __restrict__ b1,
    const unsigned short* __restrict__ W2p, const float* __restrict__ b2,
    const float* __restrict__ w_out, const float* __restrict__ b_out,
    float* __restrict__ adj, int mode)
{
    __shared__ __align__(16) char Eb[64 * PEC * 16];     // 66,560 B
    __shared__ float Pl[8][64];                          //  2,048 B

    const int tid = threadIdx.x;
    const int pr  = blockIdx.x >> 4;
    const int bc  = blockIdx.x & 15;
    int pi, pj; pair_decode(mode, pr, pi, pj);

    const int wid  = tid >> 6;
    const int l    = tid & 63;
    const int lr16 = l & 15;
    const int kq4  = l >> 4;

    const bfrag* W1c = (const bfrag*)W1p;
    const bfrag* W2c = (const bfrag*)W2p;
    const int wcb = wid * 64 + lr16;

    bfrag wb0[4], wb1[4];
    auto loadW = [&](int gs, bfrag* dst) {   // gs = global step 0..31
        const bfrag* Wc = (gs >= 16) ? W2c : W1c;
        const int base = ((gs & 15) * 4 + kq4) * 512 + wcb;
#pragma unroll
        for (int nt = 0; nt < 4; ++nt) dst[nt] = Wc[base + nt * 16];
    };

    loadW(0, wb0);

    // ---- E build: row = tid>>3 (64 rows), kc = tid&7 covers 64 k each ----
    {
        const int row = tid >> 3;
        const int kc  = tid & 7;
        const int b   = bc * 64 + row;
        const float* xi = (pi == Zi) ? (colp + b * Ff) : (nf + (b * Nn + pi) * Ff);
        const float* xj = (pj == Zi) ? (colp + b * Ff) : (nf + (b * Nn + pj) * Ff);
#pragma unroll
        for (int i = 0; i < 8; ++i) {
            const int k0 = kc * 64 + i * 8;
            const int plane = k0 >> 3;
            float4 u0 = *(const float4*)(xi + k0), u1 = *(const float4*)(xi + k0 + 4);
            float4 v0 = *(const float4*)(xj + k0), v1 = *(const float4*)(xj + k0 + 4);
            *(uint4*)(&Eb[(plane * PEC + row) * 16]) =
                pack8(u0.x*v0.x, u0.y*v0.y, u0.z*v0.z, u0.w*v0.w,
                      u1.x*v1.x, u1.y*v1.y, u1.z*v1.z, u1.w*v1.w);
        }
    }
    __syncthreads();    // E published

    f32x4 acc[4][4];
#pragma unroll
    for (int mt = 0; mt < 4; ++mt)
#pragma unroll
        for (int nt = 0; nt < 4; ++nt) acc[mt][nt] = (f32x4){0.f, 0.f, 0.f, 0.f};

#define DO_STEP(S, WB) { \
    const int ebase = ((S) & 15) * 4 + kq4; \
    bfrag a0 = *(const bfrag*)(&Eb[(ebase * PEC +      lr16) * 16]); \
    bfrag a1 = *(const bfrag*)(&Eb[(ebase * PEC + 16 + lr16) * 16]); \
    bfrag a2 = *(const bfrag*)(&Eb[(ebase * PEC + 32 + lr16) * 16]); \
    bfrag a3 = *(const bfrag*)(&Eb[(ebase * PEC + 48 + lr16) * 16]); \
    acc[0][0] = __builtin_amdgcn_mfma_f32_16x16x32_bf16(a0, WB[0], acc[0][0], 0, 0, 0); \
    acc[0][1] = __builtin_amdgcn_mfma_f32_16x16x32_bf16(a0, WB[1], acc[0][1], 0, 0, 0); \
    acc[0][2] = __builtin_amdgcn_mfma_f32_16x16x32_bf16(a0, WB[2], acc[0][2], 0, 0, 0); \
    acc[0][3] = __builtin_amdgcn_mfma_f32_16x16x32_bf16(a0, WB[3], acc[0][3], 0, 0, 0); \
    acc[1][0] = __builtin_amdgcn_mfma_f32_16x16x32_bf16(a1, WB[0], acc[1][0], 0, 0, 0); \
    acc[1][1] = __builtin_amdgcn_mfma_f32_16x16x32_bf16(a1, WB[1], acc[1][1], 0, 0, 0); \
    acc[1][2] = __builtin_amdgcn_mfma_f32_16x16x32_bf16(a1, WB[2], acc[1][2], 0, 0, 0); \
    acc[1][3] = __builtin_amdgcn_mfma_f32_16x16x32_bf16(a1, WB[3], acc[1][3], 0, 0, 0); \
    acc[2][0] = __builtin_amdgcn_mfma_f32_16x16x32_bf16(a2, WB[0], acc[2][0], 0, 0, 0); \
    acc[2][1] = __builtin_amdgcn_mfma_f32_16x16x32_bf16(a2, WB[1], acc[2][1], 0, 0, 0); \
    acc[2][2] = __builtin_amdgcn_mfma_f32_16x16x32_bf16(a2, WB[2], acc[2][2], 0, 0, 0); \
    acc[2][3] = __builtin_amdgcn_mfma_f32_16x16x32_bf16(a2, WB[3], acc[2][3], 0, 0, 0); \
    acc[3][0] = __builtin_amdgcn_mfma_f32_16x16x32_bf16(a3, WB[0], acc[3][0], 0, 0, 0); \
    acc[3][1] = __builtin_amdgcn_mfma_f32_16x16x32_bf16(a3, WB[1], acc[3][1], 0, 0, 0); \
    acc[3][2] = __builtin_amdgcn_mfma_f32_16x16x32_bf16(a3, WB[2], acc[3][2], 0, 0, 0); \
    acc[3][3] = __builtin_amdgcn_mfma_f32_16x16x32_bf16(a3, WB[3], acc[3][3], 0, 0, 0); }

    // ---- layer 1: steps 0..15 (no barriers) ----
#pragma unroll 1
    for (int s2 = 0; s2 < 8; ++s2) {
        const int s = 2 * s2;
        loadW(s + 1, wb1);
        DO_STEP(s, wb0)
        loadW(s + 2, wb0);           // s2==7 -> slice 16 = W2 slice 0
        DO_STEP(s + 1, wb1)
    }

    // ---- layer boundary: h1 = relu(acc+b1) -> Eb in place ----
    __syncthreads();                 // all layer-1 E reads done
    {
#pragma unroll
        for (int nt = 0; nt < 4; ++nt) {
            const int c  = wid * 64 + nt * 16 + lr16;
            const float bv = b1[c];
#pragma unroll
            for (int mt = 0; mt < 4; ++mt)
#pragma unroll
                for (int reg = 0; reg < 4; ++reg) {
                    int row = mt * 16 + kq4 * 4 + reg;
                    float v = fmaxf(acc[mt][nt][reg] + bv, 0.f);
                    *(unsigned short*)(&Eb[((c >> 3) * PEC + row) * 16 + (c & 7) * 2]) =
                        (unsigned short)f2bf(v);
                }
        }
#pragma unroll
        for (int mt = 0; mt < 4; ++mt)
#pragma unroll
            for (int nt = 0; nt < 4; ++nt) acc[mt][nt] = (f32x4){0.f, 0.f, 0.f, 0.f};
    }
    __syncthreads();                 // h1 published

    // ---- layer 2: steps 16..31 (no barriers) ----
#pragma unroll 1
    for (int s2 = 0; s2 < 8; ++s2) {
        const int s = 16 + 2 * s2;
        loadW(s + 1, wb1);
        DO_STEP(s, wb0)
        if (s2 < 7) loadW(s + 2, wb0);
        DO_STEP(s + 1, wb1)
    }
#undef DO_STEP

    // ---- fused layer-3: rowsum of relu(acc+b2)*w_out ----
    {
        float rs[4][4];
#pragma unroll
        for (int mt = 0; mt < 4; ++mt)
#pragma unroll
            for (int reg = 0; reg < 4; ++reg) rs[mt][reg] = 0.f;
#pragma unroll
        for (int nt = 0; nt < 4; ++nt) {
            const int c  = wid * 64 + nt * 16 + lr16;
            const float bv = b2[c];
            const float wv = w_out[c];
#pragma unroll
            for (int mt = 0; mt < 4; ++mt)
#pragma unroll
                for (int reg = 0; reg < 4; ++reg)
                    rs[mt][reg] += fmaxf(acc[mt][nt][reg] + bv, 0.f) * wv;
        }
#pragma unroll
        for (int off = 1; off < 16; off <<= 1)
#pragma unroll
            for (int mt = 0; mt < 4; ++mt)
#pragma unroll
                for (int reg = 0; reg < 4; ++reg)
                    rs[mt][reg] += __shfl_xor(rs[mt][reg], off);
        if (lr16 == 0) {
#pragma unroll
            for (int mt = 0; mt < 4; ++mt)
#pragma unroll
                for (int reg = 0; reg < 4; ++reg) {
                    int row = mt * 16 + kq4 * 4 + reg;
                    Pl[wid][row] = rs[mt][reg];
                }
        }
    }
    __syncthreads();
    if (tid < 64) {
        float v = b_out[0];
#pragma unroll
        for (int w = 0; w < 8; ++w) v += Pl[w][tid];
        int b = bc * 64 + tid;
        adj[b * (Nn * Nn) + pi * Nn + pj] = v;
        if (pi != pj) adj[b * (Nn * Nn) + pj * Nn + pi] = v;
    }
}

// ---------------------------------------------------------------------------
__global__ void softmax_az_kernel(const float* __restrict__ adj, float* __restrict__ a_z) {
    int b = blockIdx.x * 256 + threadIdx.x;
    if (b >= Bsz) return;
    const float* row = adj + b * (Nn * Nn) + Zi * Nn;
    float mx = row[0];
#pragma unroll
    for (int j = 1; j < Nn; ++j) mx = fmaxf(mx, row[j]);
    float e[Nn]; float s = 0.f;
#pragma unroll
    for (int j = 0; j < Nn; ++j) { e[j] = expf(row[j] - mx); s += e[j]; }
    float inv = 1.f / s;
#pragma unroll
    for (int j = 0; j < Nn; ++j) a_z[b * Nn + j] = e[j] * inv;
}

// ---------------------------------------------------------------------------
// mfix (fp32): m_fix[b,f] = sum_{j<10} az[j]*nf[b,j,f]  (once per t)
// ---------------------------------------------------------------------------
__global__ void mfix_kernel(const float* __restrict__ nf, const float* __restrict__ a_z,
                            float* __restrict__ m_fix) {
    int idx = blockIdx.x * 256 + threadIdx.x;   // Bsz*64
    int b = idx >> 6, kq = idx & 63;
    const float* az = a_z + b * Nn;
    const int f0 = kq * 8;
    float s0 = 0.f, s1 = 0.f, s2 = 0.f, s3 = 0.f, s4 = 0.f, s5 = 0.f, s6 = 0.f, s7 = 0.f;
#pragma unroll
    for (int j = 0; j < Nn - 1; ++j) {
        float aj = az[j];
        const float* p = nf + (b * Nn + j) * Ff + f0;
        float4 n0 = *(const float4*)p, n1 = *(const float4*)(p + 4);
        s0 += aj * n0.x; s1 += aj * n0.y; s2 += aj * n0.z; s3 += aj * n0.w;
        s4 += aj * n1.x; s5 += aj * n1.y; s6 += aj * n1.z; s7 += aj * n1.w;
    }
    *(float4*)(m_fix + b * Ff + f0)     = (float4){s0, s1, s2, s3};
    *(float4*)(m_fix + b * Ff + f0 + 4) = (float4){s4, s5, s6, s7};
}

// ---------------------------------------------------------------------------
// mzinit: m_zp = pack(m_fix + az10*col)  (once per t, before first E-step)
// ---------------------------------------------------------------------------
__global__ void mzinit_kernel(const float* __restrict__ m_fix, const float* __restrict__ a_z,
                              const float* __restrict__ col,
                              unsigned short* __restrict__ m_zp) {
    int idx = blockIdx.x * 256 + threadIdx.x;   // Bsz*64
    int b = idx >> 6, kq = idx & 63;
    const int f0 = kq * 8;
    const float az10 = a_z[b * Nn + Zi];
    float4 m0 = *(const float4*)(m_fix + b * Ff + f0);
    float4 m1 = *(const float4*)(m_fix + b * Ff + f0 + 4);
    float4 c0 = *(const float4*)(col + b * Ff + f0);
    float4 c1 = *(const float4*)(col + b * Ff + f0 + 4);
    long long dc = (((long long)(b >> 6) * 64 + kq) << 6) + (b & 63);
    *(uint4*)((char*)m_zp + dc * 16) =
        pack8(m0.x + az10*c0.x, m0.y + az10*c0.y, m0.z + az10*c0.z, m0.w + az10*c0.w,
              m1.x + az10*c1.x, m1.y + az10*c1.y, m1.z + az10*c1.z, m1.w + az10*c1.w);
}

// ---------------------------------------------------------------------------
// gates (R15-exact): gi = m_z @ Wih^T ; gh = col @ Whh^T (fp32 out).
// Block = 64 rows x 256 cols, 256 thr / 4 waves, wave tile 64x64. A staged
// once via gl_lds (linear planes); W direct global->VGPR ping-pong.
// grid (12, 16): xb<6 -> gi, else gh.
// ---------------------------------------------------------------------------
__global__ __launch_bounds__(256, 2) void gates_kernel(
    const unsigned short* __restrict__ m_zp, const unsigned short* __restrict__ colbf,
    const unsigned short* __restrict__ Wihp, const unsigned short* __restrict__ Whhp,
    float* __restrict__ gi, float* __restrict__ gh)
{
    __shared__ __align__(16) char Ab[64 * 64 * 16];   // 65,536 B

    const int xb = blockIdx.x, bc = blockIdx.y, tid = threadIdx.x;
    const bool isGi = xb < 6;
    const int nbase = (isGi ? xb : xb - 6) * 256;
    const unsigned short* Ap = isGi ? m_zp : colbf;
    const unsigned short* Wp = isGi ? Wihp : Whhp;
    float* C = isGi ? gi : gh;

    const int wid  = tid >> 6;
    const int l    = tid & 63;
    const int lr16 = l & 15;
    const int kq4  = l >> 4;

    const bfrag* Wc = (const bfrag*)Wp;
    const int wcb = ((nbase >> 9) << 15) + (nbase & 511) + wid * 64 + lr16;

    bfrag wb0[4], wb1[4];
    auto loadW = [&](int s, bfrag* dst) {   // s = step 0..15
        if (s > 15) s = 15;
        const int base = wcb + (s * 4 + kq4) * 512;
#pragma unroll
        for (int nt = 0; nt < 4; ++nt) dst[nt] = Wc[base + nt * 16];
    };

    loadW(0, wb0);

    // ---- stage A (64 KB contiguous, async, no regs) ----
#pragma unroll
    for (int i = 0; i < 16; ++i) {
        int cb = i * 256 + wid * 64;
        gl_lds16(Ap + ((long long)bc * 4096 + cb + l) * 8, (char*)Ab + cb * 16);
    }
    __syncthreads();   // drains gl_lds + W slice 0

    f32x4 acc[4][4];
#pragma unroll
    for (int mt = 0; mt < 4; ++mt)
#pragma unroll
        for (int nt = 0; nt < 4; ++nt) acc[mt][nt] = (f32x4){0.f, 0.f, 0.f, 0.f};

#define DO_STEPG(S, WB) { \
    const int ebase = (S) * 4 + kq4; \
    bfrag a0 = *(const bfrag*)(&Ab[(ebase * 64 +      lr16) * 16]); \
    bfrag a1 = *(const bfrag*)(&Ab[(ebase * 64 + 16 + lr16) * 16]); \
    bfrag a2 = *(const bfrag*)(&Ab[(ebase * 64 + 32 + lr16) * 16]); \
    bfrag a3 = *(const bfrag*)(&Ab[(ebase * 64 + 48 + lr16) * 16]); \
    acc[0][0] = __builtin_amdgcn_mfma_f32_16x16x32_bf16(a0, WB[0], acc[0][0], 0, 0, 0); \
    acc[0][1] = __builtin_amdgcn_mfma_f32_16x16x32_bf16(a0, WB[1], acc[0][1], 0, 0, 0); \
    acc[0][2] = __builtin_amdgcn_mfma_f32_16x16x32_bf16(a0, WB[2], acc[0][2], 0, 0, 0); \
    acc[0][3] = __builtin_amdgcn_mfma_f32_16x16x32_bf16(a0, WB[3], acc[0][3], 0, 0, 0); \
    acc[1][0] = __builtin_amdgcn_mfma_f32_16x16x32_bf16(a1, WB[0], acc[1][0], 0, 0, 0); \
    acc[1][1] = __builtin_amdgcn_mfma_f32_16x16x32_bf16(a1, WB[1], acc[1][1], 0, 0, 0); \
    acc[1][2] = __builtin_amdgcn_mfma_f32_16x16x32_bf16(a1, WB[2], acc[1][2], 0, 0, 0); \
    acc[1][3] = __builtin_amdgcn_mfma_f32_16x16x32_bf16(a1, WB[3], acc[1][3], 0, 0, 0); \
    acc[2][0] = __builtin_amdgcn_mfma_f32_16x16x32_bf16(a2, WB[0], acc[2][0], 0, 0, 0); \
    acc[2][1] = __builtin_amdgcn_mfma_f32_16x16x32_bf16(a2, WB[1], acc[2][1], 0, 0, 0); \
    acc[2][2] = __builtin_amdgcn_mfma_f32_16x16x32_bf16(a2, WB[2], acc[2][2], 0, 0, 0); \
    acc[2][3] = __builtin_amdgcn_mfma_f32_16x16x32_bf16(a2, WB[3], acc[2][3], 0, 0, 0); \
    acc[3][0] = __builtin_amdgcn_mfma_f32_16x16x32_bf16(a3, WB[0], acc[3][0], 0, 0, 0); \
    acc[3][1] = __builtin_amdgcn_mfma_f32_16x16x32_bf16(a3, WB[1], acc[3][1], 0, 0, 0); \
    acc[3][2] = __builtin_amdgcn_mfma_f32_16x16x32_bf16(a3, WB[2], acc[3][2], 0, 0, 0); \
    acc[3][3] = __builtin_amdgcn_mfma_f32_16x16x32_bf16(a3, WB[3], acc[3][3], 0, 0, 0); }

#pragma unroll 1
    for (int s2 = 0; s2 < 8; ++s2) {
        const int s = 2 * s2;
        loadW(s + 1, wb1);
        DO_STEPG(s, wb0)
        if (s2 < 7) loadW(s + 2, wb0);
        DO_STEPG(s + 1, wb1)
    }
#undef DO_STEPG

    // ---- epilogue: fp32 stores ----
#pragma unroll
    for (int nt = 0; nt < 4; ++nt) {
        const int c = nbase + wid * 64 + nt * 16 + lr16;
#pragma unroll
        for (int mt = 0; mt < 4; ++mt)
#pragma unroll
            for (int reg = 0; reg < 4; ++reg) {
                int row = mt * 16 + kq4 * 4 + reg;
                C[(bc * 64 + row) * G3 + c] = acc[mt][nt][reg];
            }
    }
}

// ---------------------------------------------------------------------------
// gru3: GRU pointwise + fused production of colbf AND next-step m_zp.
// ---------------------------------------------------------------------------
__global__ void gru3_kernel(const float* __restrict__ gi, const float* __restrict__ gh,
                            const float* __restrict__ m_fix, const float* __restrict__ a_z,
                            float* __restrict__ col,
                            unsigned short* __restrict__ colbf,
                            unsigned short* __restrict__ m_zp) {
    int idx = blockIdx.x * 256 + threadIdx.x;   // Bsz*64
    int b = idx >> 6, kq = idx & 63;
    const int f0 = kq * 8;
    const float* gib = gi + (long long)b * G3;
    const float* ghb = gh + (long long)b * G3;
    float4 ir0 = *(const float4*)(gib + f0),        ir1 = *(const float4*)(gib + f0 + 4);
    float4 iz0 = *(const float4*)(gib + 512 + f0),  iz1 = *(const float4*)(gib + 512 + f0 + 4);
    float4 in0 = *(const float4*)(gib + 1024 + f0), in1 = *(const float4*)(gib + 1024 + f0 + 4);
    float4 hr0 = *(const float4*)(ghb + f0),        hr1 = *(const float4*)(ghb + f0 + 4);
    float4 hz0 = *(const float4*)(ghb + 512 + f0),  hz1 = *(const float4*)(ghb + 512 + f0 + 4);
    float4 hn0 = *(const float4*)(ghb + 1024 + f0), hn1 = *(const float4*)(ghb + 1024 + f0 + 4);
    float4 h0  = *(const float4*)(col + b * Ff + f0);
    float4 h1  = *(const float4*)(col + b * Ff + f0 + 4);

    float o[8];
#define GRUC(K, IR, IZ, IN, HR, HZ, HN, H) { \
    float r = 1.f / (1.f + expf(-((IR) + (HR)))); \
    float z = 1.f / (1.f + expf(-((IZ) + (HZ)))); \
    float n = tanhf((IN) + r * (HN)); \
    o[K] = (1.f - z) * n + z * (H); }
    GRUC(0, ir0.x, iz0.x, in0.x, hr0.x, hz0.x, hn0.x, h0.x)
    GRUC(1, ir0.y, iz0.y, in0.y, hr0.y, hz0.y, hn0.y, h0.y)
    GRUC(2, ir0.z, iz0.z, in0.z, hr0.z, hz0.z, hn0.z, h0.z)
    GRUC(3, ir0.w, iz0.w, in0.w, hr0.w, hz0.w, hn0.w, h0.w)
    GRUC(4, ir1.x, iz1.x, in1.x, hr1.x, hz1.x, hn1.x, h1.x)
    GRUC(5, ir1.y, iz1.y, in1.y, hr1.y, hz1.y, hn1.y, h1.y)
    GRUC(6, ir1.z, iz1.z, in1.z, hr1.z, hz1.z, hn1.z, h1.z)
    GRUC(7, ir1.w, iz1.w, in1.w, hr1.w, hz1.w, hn1.w, h1.w)
#undef GRUC

    *(float4*)(col + b * Ff + f0)     = (float4){o[0], o[1], o[2], o[3]};
    *(float4*)(col + b * Ff + f0 + 4) = (float4){o[4], o[5], o[6], o[7]};
    long long dc = (((long long)(b >> 6) * 64 + kq) << 6) + (b & 63);
    *(uint4*)((char*)colbf + dc * 16) = pack8(o[0], o[1], o[2], o[3], o[4], o[5], o[6], o[7]);

    const float az10 = a_z[b * Nn + Zi];
    float4 m0 = *(const float4*)(m_fix + b * Ff + f0);
    float4 m1 = *(const float4*)(m_fix + b * Ff + f0 + 4);
    *(uint4*)((char*)m_zp + dc * 16) =
        pack8(m0.x + az10*o[0], m0.y + az10*o[1], m0.z + az10*o[2], m0.w + az10*o[3],
              m1.x + az10*o[4], m1.y + az10*o[5], m1.z + az10*o[6], m1.w + az10*o[7]);
}

// ---------------------------------------------------------------------------
extern "C" void kernel_launch(void* const* d_in, const int* in_sizes, int n_in,
                              void* d_out, int out_size, void* d_ws, size_t ws_size,
                              hipStream_t stream) {
    const float* nf    = (const float*)d_in[0];
    const float* W1    = (const float*)d_in[1];
    const float* b1    = (const float*)d_in[2];
    const float* W2    = (const float*)d_in[3];
    const float* b2    = (const float*)d_in[4];
    const float* w_out = (const float*)d_in[5];
    const float* b_out = (const float*)d_in[6];
    const float* W_ih  = (const float*)d_in[7];
    const float* W_hh  = (const float*)d_in[8];

    float* adj = (float*)d_out;                 // (B, 11, 11)
    float* col = adj + Bsz * Nn * Nn;           // (B, 512)

    unsigned short* W1p   = (unsigned short*)d_ws;       // packed, 512x512
    unsigned short* W2p   = W1p + Ff * Ff;
    unsigned short* Wihp  = W2p + Ff * Ff;               // packed, 1536x512
    unsigned short* Whhp  = Wihp + G3 * Ff;
    float* a_z            = (float*)(Whhp + G3 * Ff);    // 16384 floats
    float* m_fix          = a_z + 16384;                 // B*512 fp32
    unsigned short* m_zp  = (unsigned short*)(m_fix + Bsz * Ff);  // B*512 packed
    unsigned short* colbf = m_zp + Bsz * Ff;                      // B*512 packed
    float* gi             = (float*)(colbf + Bsz * Ff);  // B*1536
    float* gh             = gi + Bsz * G3;               // B*1536

    init_col2_kernel<<<(Bsz * 64) / 256, 256, 0, stream>>>(nf, col, colbf);
    pack_w_kernel<<<(Ff * 64) / 256, 256, 0, stream>>>(W1, W1p, 9);
    pack_w_kernel<<<(Ff * 64) / 256, 256, 0, stream>>>(W2, W2p, 9);
    pack_w_kernel<<<(G3 * 64) / 256, 256, 0, stream>>>(W_ih, Wihp, 9);
    pack_w_kernel<<<(G3 * 64) / 256, 256, 0, stream>>>(W_hh, Whhp, 9);

    for (int t = 0; t < 3; ++t) {
        const int mode   = (t == 0) ? 0 : 1;
        const int npairs = (t == 0) ? 66 : 11;

        link_kernel<<<npairs * 16, 512, 0, stream>>>(nf, col, W1p, b1, W2p, b2,
                                                     w_out, b_out, adj, mode);
        softmax_az_kernel<<<Bsz / 256, 256, 0, stream>>>(adj, a_z);
        mfix_kernel<<<(Bsz * 64) / 256, 256, 0, stream>>>(nf, a_z, m_fix);
        mzinit_kernel<<<(Bsz * 64) / 256, 256, 0, stream>>>(m_fix, a_z, col, m_zp);

        for (int s = 0; s < 3; ++s) {
            gates_kernel<<<dim3(12, 16), 256, 0, stream>>>(m_zp, colbf, Wihp, Whhp, gi, gh);
            gru3_kernel<<<(Bsz * 64) / 256, 256, 0, stream>>>(gi, gh, m_fix, a_z,
                                                              col, colbf, m_zp);
        }
    }
}

// Round 21
// 335.651 us; speedup vs baseline: 1.3221x; 1.0908x over previous
//
#include <hip/hip_runtime.h>
#include <hip/hip_bf16.h>
#include <math.h>

#define Bsz 1024
#define Nn  11
#define Ff  512
#define Zi  10
#define G3  1536

#define PEC 65    // link Eb plane stride (64 rows + 1 pad chunk)

typedef __attribute__((ext_vector_type(8))) short bfrag;
typedef __attribute__((ext_vector_type(4))) float f32x4;

__device__ __forceinline__ unsigned f2bf(float f) {
    __hip_bfloat16 h = __float2bfloat16(f);
    return (unsigned)*reinterpret_cast<unsigned short*>(&h);
}
__device__ __forceinline__ float bf2f(unsigned short u) {
    union { unsigned int i; float f; } v;
    v.i = ((unsigned int)u) << 16;
    return v.f;
}
__device__ __forceinline__ uint4 pack8(float v0, float v1, float v2, float v3,
                                       float v4, float v5, float v6, float v7) {
    uint4 pk;
    pk.x = f2bf(v0) | (f2bf(v1) << 16);
    pk.y = f2bf(v2) | (f2bf(v3) << 16);
    pk.z = f2bf(v4) | (f2bf(v5) << 16);
    pk.w = f2bf(v6) | (f2bf(v7) << 16);
    return pk;
}
__device__ __forceinline__ void pair_decode(int mode, int p, int& pi, int& pj) {
    if (mode == 0) { int r = p, i = 0; while (r >= Nn - i) { r -= Nn - i; ++i; } pi = i; pj = i + r; }
    else { pi = p; pj = Zi; }
}
// async global->LDS, 16B/lane; dst must be wave-uniform base (+lane*16 by HW)
__device__ __forceinline__ void gl_lds16(const void* src, void* dst) {
    __builtin_amdgcn_global_load_lds((const __attribute__((address_space(1))) void*)src,
                                     (__attribute__((address_space(3))) void*)dst, 16, 0, 0);
}

// ---------------------------------------------------------------------------
// init: col fp32 AND colbf (packed bf16, kq-plane-major per 64-row block)
// ---------------------------------------------------------------------------
__global__ void init_col2_kernel(const float* __restrict__ nf, float* __restrict__ col,
                                 unsigned short* __restrict__ colbf) {
    int idx = blockIdx.x * 256 + threadIdx.x;   // Bsz*64
    int b = idx >> 6, kq = idx & 63;
    const float* s = nf + (b * Nn + Zi) * Ff + kq * 8;
    float4 a = *(const float4*)s, c = *(const float4*)(s + 4);
    *(float4*)(col + b * Ff + kq * 8)     = a;
    *(float4*)(col + b * Ff + kq * 8 + 4) = c;
    long long dc = (((long long)(b >> 6) * 64 + kq) << 6) + (b & 63);
    *(uint4*)((char*)colbf + dc * 16) = pack8(a.x, a.y, a.z, a.w, c.x, c.y, c.z, c.w);
}

// ---------------------------------------------------------------------------
// pack fp32 W[g][k] -> bf16 kq-plane-major chunks (contiguous/coalescable)
// ---------------------------------------------------------------------------
__global__ void pack_w_kernel(const float* __restrict__ src,
                              unsigned short* __restrict__ dst, int lgBW) {
    int idx = blockIdx.x * 256 + threadIdx.x;   // total G*64 chunks
    int g = idx >> 6, kq = idx & 63;
    int nb = g >> lgBW, gl = g & ((1 << lgBW) - 1);
    const float* s = src + g * Ff + kq * 8;
    float4 a = *(const float4*)s, b = *(const float4*)(s + 4);
    uint4 pk = pack8(a.x, a.y, a.z, a.w, b.x, b.y, b.z, b.w);
    long long dc = (((long long)(nb << 6) + kq) << lgBW) + gl;
    *(uint4*)((char*)dst + dc * 16) = pk;
}

// ---------------------------------------------------------------------------
// Fused link MLP (R15-exact). Block = 64 rows x 512 cols, 512 thr / 8 waves;
// wave tile 64x64 = 4x4 of mfma_f32_16x16x32_bf16. E resident in LDS; W
// direct global->VGPR ping-pong. 3 barriers total. LDS 68.6 KB.
// ---------------------------------------------------------------------------
__global__ __launch_bounds__(512, 2) void link_kernel(
    const float* __restrict__ nf, const float* __restrict__ colp,
    const unsigned short* __restrict__ W1p, const float* __restrict__ b1,
    const unsigned short* __restrict__ W2p, const float* __restrict__ b2,
    const float* __restrict__ w_out, const float* __restrict__ b_out,
    float* __restrict__ adj, int mode)
{
    __shared__ __align__(16) char Eb[64 * PEC * 16];     // 66,560 B
    __shared__ float Pl[8][64];                          //  2,048 B

    const int tid = threadIdx.x;
    const int pr  = blockIdx.x >> 4;
    const int bc  = blockIdx.x & 15;
    int pi, pj; pair_decode(mode, pr, pi, pj);

    const int wid  = tid >> 6;
    const int l    = tid & 63;
    const int lr16 = l & 15;
    const int kq4  = l >> 4;

    const bfrag* W1c = (const bfrag*)W1p;
    const bfrag* W2c = (const bfrag*)W2p;
    const int wcb = wid * 64 + lr16;

    bfrag wb0[4], wb1[4];
    auto loadW = [&](int gs, bfrag* dst) {   // gs = global step 0..31
        const bfrag* Wc = (gs >= 16) ? W2c : W1c;
        const int base = ((gs & 15) * 4 + kq4) * 512 + wcb;
#pragma unroll
        for (int nt = 0; nt < 4; ++nt) dst[nt] = Wc[base + nt * 16];
    };

    loadW(0, wb0);

    // ---- E build: row = tid>>3 (64 rows), kc = tid&7 covers 64 k each ----
    {
        const int row = tid >> 3;
        const int kc  = tid & 7;
        const int b   = bc * 64 + row;
        const float* xi = (pi == Zi) ? (colp + b * Ff) : (nf + (b * Nn + pi) * Ff);
        const float* xj = (pj == Zi) ? (colp + b * Ff) : (nf + (b * Nn + pj) * Ff);
#pragma unroll
        for (int i = 0; i < 8; ++i) {
            const int k0 = kc * 64 + i * 8;
            const int plane = k0 >> 3;
            float4 u0 = *(const float4*)(xi + k0), u1 = *(const float4*)(xi + k0 + 4);
            float4 v0 = *(const float4*)(xj + k0), v1 = *(const float4*)(xj + k0 + 4);
            *(uint4*)(&Eb[(plane * PEC + row) * 16]) =
                pack8(u0.x*v0.x, u0.y*v0.y, u0.z*v0.z, u0.w*v0.w,
                      u1.x*v1.x, u1.y*v1.y, u1.z*v1.z, u1.w*v1.w);
        }
    }
    __syncthreads();    // E published

    f32x4 acc[4][4];
#pragma unroll
    for (int mt = 0; mt < 4; ++mt)
#pragma unroll
        for (int nt = 0; nt < 4; ++nt) acc[mt][nt] = (f32x4){0.f, 0.f, 0.f, 0.f};

#define DO_STEP(S, WB) { \
    const int ebase = ((S) & 15) * 4 + kq4; \
    bfrag a0 = *(const bfrag*)(&Eb[(ebase * PEC +      lr16) * 16]); \
    bfrag a1 = *(const bfrag*)(&Eb[(ebase * PEC + 16 + lr16) * 16]); \
    bfrag a2 = *(const bfrag*)(&Eb[(ebase * PEC + 32 + lr16) * 16]); \
    bfrag a3 = *(const bfrag*)(&Eb[(ebase * PEC + 48 + lr16) * 16]); \
    acc[0][0] = __builtin_amdgcn_mfma_f32_16x16x32_bf16(a0, WB[0], acc[0][0], 0, 0, 0); \
    acc[0][1] = __builtin_amdgcn_mfma_f32_16x16x32_bf16(a0, WB[1], acc[0][1], 0, 0, 0); \
    acc[0][2] = __builtin_amdgcn_mfma_f32_16x16x32_bf16(a0, WB[2], acc[0][2], 0, 0, 0); \
    acc[0][3] = __builtin_amdgcn_mfma_f32_16x16x32_bf16(a0, WB[3], acc[0][3], 0, 0, 0); \
    acc[1][0] = __builtin_amdgcn_mfma_f32_16x16x32_bf16(a1, WB[0], acc[1][0], 0, 0, 0); \
    acc[1][1] = __builtin_amdgcn_mfma_f32_16x16x32_bf16(a1, WB[1], acc[1][1], 0, 0, 0); \
    acc[1][2] = __builtin_amdgcn_mfma_f32_16x16x32_bf16(a1, WB[2], acc[1][2], 0, 0, 0); \
    acc[1][3] = __builtin_amdgcn_mfma_f32_16x16x32_bf16(a1, WB[3], acc[1][3], 0, 0, 0); \
    acc[2][0] = __builtin_amdgcn_mfma_f32_16x16x32_bf16(a2, WB[0], acc[2][0], 0, 0, 0); \
    acc[2][1] = __builtin_amdgcn_mfma_f32_16x16x32_bf16(a2, WB[1], acc[2][1], 0, 0, 0); \
    acc[2][2] = __builtin_amdgcn_mfma_f32_16x16x32_bf16(a2, WB[2], acc[2][2], 0, 0, 0); \
    acc[2][3] = __builtin_amdgcn_mfma_f32_16x16x32_bf16(a2, WB[3], acc[2][3], 0, 0, 0); \
    acc[3][0] = __builtin_amdgcn_mfma_f32_16x16x32_bf16(a3, WB[0], acc[3][0], 0, 0, 0); \
    acc[3][1] = __builtin_amdgcn_mfma_f32_16x16x32_bf16(a3, WB[1], acc[3][1], 0, 0, 0); \
    acc[3][2] = __builtin_amdgcn_mfma_f32_16x16x32_bf16(a3, WB[2], acc[3][2], 0, 0, 0); \
    acc[3][3] = __builtin_amdgcn_mfma_f32_16x16x32_bf16(a3, WB[3], acc[3][3], 0, 0, 0); }

    // ---- layer 1: steps 0..15 (no barriers) ----
#pragma unroll 1
    for (int s2 = 0; s2 < 8; ++s2) {
        const int s = 2 * s2;
        loadW(s + 1, wb1);
        DO_STEP(s, wb0)
        loadW(s + 2, wb0);           // s2==7 -> slice 16 = W2 slice 0
        DO_STEP(s + 1, wb1)
    }

    // ---- layer boundary: h1 = relu(acc+b1) -> Eb in place ----
    __syncthreads();                 // all layer-1 E reads done
    {
#pragma unroll
        for (int nt = 0; nt < 4; ++nt) {
            const int c  = wid * 64 + nt * 16 + lr16;
            const float bv = b1[c];
#pragma unroll
            for (int mt = 0; mt < 4; ++mt)
#pragma unroll
                for (int reg = 0; reg < 4; ++reg) {
                    int row = mt * 16 + kq4 * 4 + reg;
                    float v = fmaxf(acc[mt][nt][reg] + bv, 0.f);
                    *(unsigned short*)(&Eb[((c >> 3) * PEC + row) * 16 + (c & 7) * 2]) =
                        (unsigned short)f2bf(v);
                }
        }
#pragma unroll
        for (int mt = 0; mt < 4; ++mt)
#pragma unroll
            for (int nt = 0; nt < 4; ++nt) acc[mt][nt] = (f32x4){0.f, 0.f, 0.f, 0.f};
    }
    __syncthreads();                 // h1 published

    // ---- layer 2: steps 16..31 (no barriers) ----
#pragma unroll 1
    for (int s2 = 0; s2 < 8; ++s2) {
        const int s = 16 + 2 * s2;
        loadW(s + 1, wb1);
        DO_STEP(s, wb0)
        if (s2 < 7) loadW(s + 2, wb0);
        DO_STEP(s + 1, wb1)
    }
#undef DO_STEP

    // ---- fused layer-3: rowsum of relu(acc+b2)*w_out ----
    {
        float rs[4][4];
#pragma unroll
        for (int mt = 0; mt < 4; ++mt)
#pragma unroll
            for (int reg = 0; reg < 4; ++reg) rs[mt][reg] = 0.f;
#pragma unroll
        for (int nt = 0; nt < 4; ++nt) {
            const int c  = wid * 64 + nt * 16 + lr16;
            const float bv = b2[c];
            const float wv = w_out[c];
#pragma unroll
            for (int mt = 0; mt < 4; ++mt)
#pragma unroll
                for (int reg = 0; reg < 4; ++reg)
                    rs[mt][reg] += fmaxf(acc[mt][nt][reg] + bv, 0.f) * wv;
        }
#pragma unroll
        for (int off = 1; off < 16; off <<= 1)
#pragma unroll
            for (int mt = 0; mt < 4; ++mt)
#pragma unroll
                for (int reg = 0; reg < 4; ++reg)
                    rs[mt][reg] += __shfl_xor(rs[mt][reg], off);
        if (lr16 == 0) {
#pragma unroll
            for (int mt = 0; mt < 4; ++mt)
#pragma unroll
                for (int reg = 0; reg < 4; ++reg) {
                    int row = mt * 16 + kq4 * 4 + reg;
                    Pl[wid][row] = rs[mt][reg];
                }
        }
    }
    __syncthreads();
    if (tid < 64) {
        float v = b_out[0];
#pragma unroll
        for (int w = 0; w < 8; ++w) v += Pl[w][tid];
        int b = bc * 64 + tid;
        adj[b * (Nn * Nn) + pi * Nn + pj] = v;
        if (pi != pj) adj[b * (Nn * Nn) + pj * Nn + pi] = v;
    }
}

// ---------------------------------------------------------------------------
// azmix: fused softmax(row Zi) + m_fix + m_zp-init.  grid Bsz*64/256.
// Each thread recomputes the 11-wide softmax (redundant, cheap); kq<11
// threads store a_z. m_fix fp32 + m_zp packed written per (b, kq).
// ---------------------------------------------------------------------------
__global__ void azmix_kernel(const float* __restrict__ adj, const float* __restrict__ nf,
                             const float* __restrict__ col,
                             float* __restrict__ a_z, float* __restrict__ m_fix,
                             unsigned short* __restrict__ m_zp) {
    int idx = blockIdx.x * 256 + threadIdx.x;   // Bsz*64
    int b = idx >> 6, kq = idx & 63;
    const float* row = adj + b * (Nn * Nn) + Zi * Nn;
    float az[Nn];
    {
        float mx = row[0];
#pragma unroll
        for (int j = 1; j < Nn; ++j) mx = fmaxf(mx, row[j]);
        float s = 0.f;
#pragma unroll
        for (int j = 0; j < Nn; ++j) { az[j] = expf(row[j] - mx); s += az[j]; }
        float inv = 1.f / s;
#pragma unroll
        for (int j = 0; j < Nn; ++j) az[j] *= inv;
    }
    if (kq < Nn) a_z[b * Nn + kq] = az[kq];

    const int f0 = kq * 8;
    float s0 = 0.f, s1 = 0.f, s2 = 0.f, s3 = 0.f, s4 = 0.f, s5 = 0.f, s6 = 0.f, s7 = 0.f;
#pragma unroll
    for (int j = 0; j < Nn - 1; ++j) {
        float aj = az[j];
        const float* p = nf + (b * Nn + j) * Ff + f0;
        float4 n0 = *(const float4*)p, n1 = *(const float4*)(p + 4);
        s0 += aj * n0.x; s1 += aj * n0.y; s2 += aj * n0.z; s3 += aj * n0.w;
        s4 += aj * n1.x; s5 += aj * n1.y; s6 += aj * n1.z; s7 += aj * n1.w;
    }
    *(float4*)(m_fix + b * Ff + f0)     = (float4){s0, s1, s2, s3};
    *(float4*)(m_fix + b * Ff + f0 + 4) = (float4){s4, s5, s6, s7};

    const float az10 = az[Zi];
    float4 c0 = *(const float4*)(col + b * Ff + f0);
    float4 c1 = *(const float4*)(col + b * Ff + f0 + 4);
    long long dc = (((long long)(b >> 6) * 64 + kq) << 6) + (b & 63);
    *(uint4*)((char*)m_zp + dc * 16) =
        pack8(s0 + az10*c0.x, s1 + az10*c0.y, s2 + az10*c0.z, s3 + az10*c0.w,
              s4 + az10*c1.x, s5 + az10*c1.y, s6 + az10*c1.z, s7 + az10*c1.w);
}

// ---------------------------------------------------------------------------
// gates: gi = m_z @ Wih^T ; gh = col @ Whh^T -> bf16 out.
// Block = 64 rows x 256 cols, 256 thr / 4 waves, wave tile 64x64. A staged
// once via gl_lds (linear planes); W direct global->VGPR ping-pong.
// grid (12, 16): xb<6 -> gi, else gh.
// ---------------------------------------------------------------------------
__global__ __launch_bounds__(256, 2) void gates_kernel(
    const unsigned short* __restrict__ m_zp, const unsigned short* __restrict__ colbf,
    const unsigned short* __restrict__ Wihp, const unsigned short* __restrict__ Whhp,
    unsigned short* __restrict__ gi, unsigned short* __restrict__ gh)
{
    __shared__ __align__(16) char Ab[64 * 64 * 16];   // 65,536 B

    const int xb = blockIdx.x, bc = blockIdx.y, tid = threadIdx.x;
    const bool isGi = xb < 6;
    const int nbase = (isGi ? xb : xb - 6) * 256;
    const unsigned short* Ap = isGi ? m_zp : colbf;
    const unsigned short* Wp = isGi ? Wihp : Whhp;
    unsigned short* C = isGi ? gi : gh;

    const int wid  = tid >> 6;
    const int l    = tid & 63;
    const int lr16 = l & 15;
    const int kq4  = l >> 4;

    const bfrag* Wc = (const bfrag*)Wp;
    const int wcb = ((nbase >> 9) << 15) + (nbase & 511) + wid * 64 + lr16;

    bfrag wb0[4], wb1[4];
    auto loadW = [&](int s, bfrag* dst) {   // s = step 0..15
        if (s > 15) s = 15;
        const int base = wcb + (s * 4 + kq4) * 512;
#pragma unroll
        for (int nt = 0; nt < 4; ++nt) dst[nt] = Wc[base + nt * 16];
    };

    loadW(0, wb0);

    // ---- stage A (64 KB contiguous, async, no regs) ----
#pragma unroll
    for (int i = 0; i < 16; ++i) {
        int cb = i * 256 + wid * 64;
        gl_lds16(Ap + ((long long)bc * 4096 + cb + l) * 8, (char*)Ab + cb * 16);
    }
    __syncthreads();   // drains gl_lds + W slice 0

    f32x4 acc[4][4];
#pragma unroll
    for (int mt = 0; mt < 4; ++mt)
#pragma unroll
        for (int nt = 0; nt < 4; ++nt) acc[mt][nt] = (f32x4){0.f, 0.f, 0.f, 0.f};

#define DO_STEPG(S, WB) { \
    const int ebase = (S) * 4 + kq4; \
    bfrag a0 = *(const bfrag*)(&Ab[(ebase * 64 +      lr16) * 16]); \
    bfrag a1 = *(const bfrag*)(&Ab[(ebase * 64 + 16 + lr16) * 16]); \
    bfrag a2 = *(const bfrag*)(&Ab[(ebase * 64 + 32 + lr16) * 16]); \
    bfrag a3 = *(const bfrag*)(&Ab[(ebase * 64 + 48 + lr16) * 16]); \
    acc[0][0] = __builtin_amdgcn_mfma_f32_16x16x32_bf16(a0, WB[0], acc[0][0], 0, 0, 0); \
    acc[0][1] = __builtin_amdgcn_mfma_f32_16x16x32_bf16(a0, WB[1], acc[0][1], 0, 0, 0); \
    acc[0][2] = __builtin_amdgcn_mfma_f32_16x16x32_bf16(a0, WB[2], acc[0][2], 0, 0, 0); \
    acc[0][3] = __builtin_amdgcn_mfma_f32_16x16x32_bf16(a0, WB[3], acc[0][3], 0, 0, 0); \
    acc[1][0] = __builtin_amdgcn_mfma_f32_16x16x32_bf16(a1, WB[0], acc[1][0], 0, 0, 0); \
    acc[1][1] = __builtin_amdgcn_mfma_f32_16x16x32_bf16(a1, WB[1], acc[1][1], 0, 0, 0); \
    acc[1][2] = __builtin_amdgcn_mfma_f32_16x16x32_bf16(a1, WB[2], acc[1][2], 0, 0, 0); \
    acc[1][3] = __builtin_amdgcn_mfma_f32_16x16x32_bf16(a1, WB[3], acc[1][3], 0, 0, 0); \
    acc[2][0] = __builtin_amdgcn_mfma_f32_16x16x32_bf16(a2, WB[0], acc[2][0], 0, 0, 0); \
    acc[2][1] = __builtin_amdgcn_mfma_f32_16x16x32_bf16(a2, WB[1], acc[2][1], 0, 0, 0); \
    acc[2][2] = __builtin_amdgcn_mfma_f32_16x16x32_bf16(a2, WB[2], acc[2][2], 0, 0, 0); \
    acc[2][3] = __builtin_amdgcn_mfma_f32_16x16x32_bf16(a2, WB[3], acc[2][3], 0, 0, 0); \
    acc[3][0] = __builtin_amdgcn_mfma_f32_16x16x32_bf16(a3, WB[0], acc[3][0], 0, 0, 0); \
    acc[3][1] = __builtin_amdgcn_mfma_f32_16x16x32_bf16(a3, WB[1], acc[3][1], 0, 0, 0); \
    acc[3][2] = __builtin_amdgcn_mfma_f32_16x16x32_bf16(a3, WB[2], acc[3][2], 0, 0, 0); \
    acc[3][3] = __builtin_amdgcn_mfma_f32_16x16x32_bf16(a3, WB[3], acc[3][3], 0, 0, 0); }

#pragma unroll 1
    for (int s2 = 0; s2 < 8; ++s2) {
        const int s = 2 * s2;
        loadW(s + 1, wb1);
        DO_STEPG(s, wb0)
        if (s2 < 7) loadW(s + 2, wb0);
        DO_STEPG(s + 1, wb1)
    }
#undef DO_STEPG

    // ---- epilogue: bf16 stores ----
#pragma unroll
    for (int nt = 0; nt < 4; ++nt) {
        const int c = nbase + wid * 64 + nt * 16 + lr16;
#pragma unroll
        for (int mt = 0; mt < 4; ++mt)
#pragma unroll
            for (int reg = 0; reg < 4; ++reg) {
                int row = mt * 16 + kq4 * 4 + reg;
                C[(long long)(bc * 64 + row) * G3 + c] = (unsigned short)f2bf(acc[mt][nt][reg]);
            }
    }
}

// ---------------------------------------------------------------------------
// gru3: GRU pointwise (bf16 gate inputs) + fused colbf AND next-step m_zp.
// ---------------------------------------------------------------------------
__global__ void gru3_kernel(const unsigned short* __restrict__ gi,
                            const unsigned short* __restrict__ gh,
                            const float* __restrict__ m_fix, const float* __restrict__ a_z,
                            float* __restrict__ col,
                            unsigned short* __restrict__ colbf,
                            unsigned short* __restrict__ m_zp) {
    int idx = blockIdx.x * 256 + threadIdx.x;   // Bsz*64
    int b = idx >> 6, kq = idx & 63;
    const int f0 = kq * 8;
    const unsigned short* gib = gi + (long long)b * G3;
    const unsigned short* ghb = gh + (long long)b * G3;

    uint4 irp = *(const uint4*)(gib + f0);
    uint4 izp = *(const uint4*)(gib + 512 + f0);
    uint4 inp = *(const uint4*)(gib + 1024 + f0);
    uint4 hrp = *(const uint4*)(ghb + f0);
    uint4 hzp = *(const uint4*)(ghb + 512 + f0);
    uint4 hnp = *(const uint4*)(ghb + 1024 + f0);
    float4 h0 = *(const float4*)(col + b * Ff + f0);
    float4 h1 = *(const float4*)(col + b * Ff + f0 + 4);
    float hv[8] = {h0.x, h0.y, h0.z, h0.w, h1.x, h1.y, h1.z, h1.w};

    const unsigned* irw = (const unsigned*)&irp;
    const unsigned* izw = (const unsigned*)&izp;
    const unsigned* inw = (const unsigned*)&inp;
    const unsigned* hrw = (const unsigned*)&hrp;
    const unsigned* hzw = (const unsigned*)&hzp;
    const unsigned* hnw = (const unsigned*)&hnp;

    float o[8];
#pragma unroll
    for (int k = 0; k < 8; ++k) {
        const int w = k >> 1, hi = k & 1;
        float ir = bf2f((unsigned short)(irw[w] >> (hi * 16)));
        float iz = bf2f((unsigned short)(izw[w] >> (hi * 16)));
        float in = bf2f((unsigned short)(inw[w] >> (hi * 16)));
        float hr = bf2f((unsigned short)(hrw[w] >> (hi * 16)));
        float hz = bf2f((unsigned short)(hzw[w] >> (hi * 16)));
        float hn = bf2f((unsigned short)(hnw[w] >> (hi * 16)));
        float r = 1.f / (1.f + expf(-(ir + hr)));
        float z = 1.f / (1.f + expf(-(iz + hz)));
        float n = tanhf(in + r * hn);
        o[k] = (1.f - z) * n + z * hv[k];
    }

    *(float4*)(col + b * Ff + f0)     = (float4){o[0], o[1], o[2], o[3]};
    *(float4*)(col + b * Ff + f0 + 4) = (float4){o[4], o[5], o[6], o[7]};
    long long dc = (((long long)(b >> 6) * 64 + kq) << 6) + (b & 63);
    *(uint4*)((char*)colbf + dc * 16) = pack8(o[0], o[1], o[2], o[3], o[4], o[5], o[6], o[7]);

    const float az10 = a_z[b * Nn + Zi];
    float4 m0 = *(const float4*)(m_fix + b * Ff + f0);
    float4 m1 = *(const float4*)(m_fix + b * Ff + f0 + 4);
    *(uint4*)((char*)m_zp + dc * 16) =
        pack8(m0.x + az10*o[0], m0.y + az10*o[1], m0.z + az10*o[2], m0.w + az10*o[3],
              m1.x + az10*o[4], m1.y + az10*o[5], m1.z + az10*o[6], m1.w + az10*o[7]);
}

// ---------------------------------------------------------------------------
extern "C" void kernel_launch(void* const* d_in, const int* in_sizes, int n_in,
                              void* d_out, int out_size, void* d_ws, size_t ws_size,
                              hipStream_t stream) {
    const float* nf    = (const float*)d_in[0];
    const float* W1    = (const float*)d_in[1];
    const float* b1    = (const float*)d_in[2];
    const float* W2    = (const float*)d_in[3];
    const float* b2    = (const float*)d_in[4];
    const float* w_out = (const float*)d_in[5];
    const float* b_out = (const float*)d_in[6];
    const float* W_ih  = (const float*)d_in[7];
    const float* W_hh  = (const float*)d_in[8];

    float* adj = (float*)d_out;                 // (B, 11, 11)
    float* col = adj + Bsz * Nn * Nn;           // (B, 512)

    unsigned short* W1p   = (unsigned short*)d_ws;       // packed, 512x512
    unsigned short* W2p   = W1p + Ff * Ff;
    unsigned short* Wihp  = W2p + Ff * Ff;               // packed, 1536x512
    unsigned short* Whhp  = Wihp + G3 * Ff;
    float* a_z            = (float*)(Whhp + G3 * Ff);    // 16384 floats
    float* m_fix          = a_z + 16384;                 // B*512 fp32
    unsigned short* m_zp  = (unsigned short*)(m_fix + Bsz * Ff);  // B*512 packed
    unsigned short* colbf = m_zp + Bsz * Ff;                      // B*512 packed
    unsigned short* gi    = colbf + Bsz * Ff;            // B*1536 bf16
    unsigned short* gh    = gi + (long long)Bsz * G3;    // B*1536 bf16

    init_col2_kernel<<<(Bsz * 64) / 256, 256, 0, stream>>>(nf, col, colbf);
    pack_w_kernel<<<(Ff * 64) / 256, 256, 0, stream>>>(W1, W1p, 9);
    pack_w_kernel<<<(Ff * 64) / 256, 256, 0, stream>>>(W2, W2p, 9);
    pack_w_kernel<<<(G3 * 64) / 256, 256, 0, stream>>>(W_ih, Wihp, 9);
    pack_w_kernel<<<(G3 * 64) / 256, 256, 0, stream>>>(W_hh, Whhp, 9);

    for (int t = 0; t < 3; ++t) {
        const int mode   = (t == 0) ? 0 : 1;
        const int npairs = (t == 0) ? 66 : 11;

        link_kernel<<<npairs * 16, 512, 0, stream>>>(nf, col, W1p, b1, W2p, b2,
                                                     w_out, b_out, adj, mode);
        azmix_kernel<<<(Bsz * 64) / 256, 256, 0, stream>>>(adj, nf, col, a_z, m_fix, m_zp);

        for (int s = 0; s < 3; ++s) {
            gates_kernel<<<dim3(12, 16), 256, 0, stream>>>(m_zp, colbf, Wihp, Whhp, gi, gh);
            gru3_kernel<<<(Bsz * 64) / 256, 256, 0, stream>>>(gi, gh, m_fix, a_z,
                                                              col, colbf, m_zp);
        }
    }
}

// Round 22
// 322.139 us; speedup vs baseline: 1.3776x; 1.0419x over previous
//
#include <hip/hip_runtime.h>
#include <hip/hip_bf16.h>
#include <math.h>

#define Bsz 1024
#define Nn  11
#define Ff  512
#define Zi  10
#define G3  1536

#define PEC 65    // link Eb plane stride (64 rows + 1 pad chunk)

typedef __attribute__((ext_vector_type(8))) short bfrag;
typedef __attribute__((ext_vector_type(4))) float f32x4;

__device__ __forceinline__ unsigned f2bf(float f) {
    __hip_bfloat16 h = __float2bfloat16(f);
    return (unsigned)*reinterpret_cast<unsigned short*>(&h);
}
__device__ __forceinline__ float bf2f(unsigned short u) {
    union { unsigned int i; float f; } v;
    v.i = ((unsigned int)u) << 16;
    return v.f;
}
__device__ __forceinline__ uint4 pack8(float v0, float v1, float v2, float v3,
                                       float v4, float v5, float v6, float v7) {
    uint4 pk;
    pk.x = f2bf(v0) | (f2bf(v1) << 16);
    pk.y = f2bf(v2) | (f2bf(v3) << 16);
    pk.z = f2bf(v4) | (f2bf(v5) << 16);
    pk.w = f2bf(v6) | (f2bf(v7) << 16);
    return pk;
}
__device__ __forceinline__ void pair_decode(int mode, int p, int& pi, int& pj) {
    if (mode == 0) { int r = p, i = 0; while (r >= Nn - i) { r -= Nn - i; ++i; } pi = i; pj = i + r; }
    else { pi = p; pj = Zi; }
}
// async global->LDS, 16B/lane; dst must be wave-uniform base (+lane*16 by HW)
__device__ __forceinline__ void gl_lds16(const void* src, void* dst) {
    __builtin_amdgcn_global_load_lds((const __attribute__((address_space(1))) void*)src,
                                     (__attribute__((address_space(3))) void*)dst, 16, 0, 0);
}

// ---------------------------------------------------------------------------
// init: col fp32 AND colbf (packed bf16, kq-plane-major per 64-row block)
// ---------------------------------------------------------------------------
__global__ void init_col2_kernel(const float* __restrict__ nf, float* __restrict__ col,
                                 unsigned short* __restrict__ colbf) {
    int idx = blockIdx.x * 256 + threadIdx.x;   // Bsz*64
    int b = idx >> 6, kq = idx & 63;
    const float* s = nf + (b * Nn + Zi) * Ff + kq * 8;
    float4 a = *(const float4*)s, c = *(const float4*)(s + 4);
    *(float4*)(col + b * Ff + kq * 8)     = a;
    *(float4*)(col + b * Ff + kq * 8 + 4) = c;
    long long dc = (((long long)(b >> 6) * 64 + kq) << 6) + (b & 63);
    *(uint4*)((char*)colbf + dc * 16) = pack8(a.x, a.y, a.z, a.w, c.x, c.y, c.z, c.w);
}

// ---------------------------------------------------------------------------
// pack fp32 W[g][k] -> bf16 kq-plane-major chunks (contiguous/coalescable)
// ---------------------------------------------------------------------------
__global__ void pack_w_kernel(const float* __restrict__ src,
                              unsigned short* __restrict__ dst, int lgBW) {
    int idx = blockIdx.x * 256 + threadIdx.x;   // total G*64 chunks
    int g = idx >> 6, kq = idx & 63;
    int nb = g >> lgBW, gl = g & ((1 << lgBW) - 1);
    const float* s = src + g * Ff + kq * 8;
    float4 a = *(const float4*)s, b = *(const float4*)(s + 4);
    uint4 pk = pack8(a.x, a.y, a.z, a.w, b.x, b.y, b.z, b.w);
    long long dc = (((long long)(nb << 6) + kq) << lgBW) + gl;
    *(uint4*)((char*)dst + dc * 16) = pk;
}

// ---------------------------------------------------------------------------
// Fused link MLP (R15-exact). Block = 64 rows x 512 cols, 512 thr / 8 waves;
// wave tile 64x64 = 4x4 of mfma_f32_16x16x32_bf16. E resident in LDS; W
// direct global->VGPR ping-pong. 3 barriers total. LDS 68.6 KB.
// ---------------------------------------------------------------------------
__global__ __launch_bounds__(512, 2) void link_kernel(
    const float* __restrict__ nf, const float* __restrict__ colp,
    const unsigned short* __restrict__ W1p, const float* __restrict__ b1,
    const unsigned short* __restrict__ W2p, const float* __restrict__ b2,
    const float* __restrict__ w_out, const float* __restrict__ b_out,
    float* __restrict__ adj, int mode)
{
    __shared__ __align__(16) char Eb[64 * PEC * 16];     // 66,560 B
    __shared__ float Pl[8][64];                          //  2,048 B

    const int tid = threadIdx.x;
    const int pr  = blockIdx.x >> 4;
    const int bc  = blockIdx.x & 15;
    int pi, pj; pair_decode(mode, pr, pi, pj);

    const int wid  = tid >> 6;
    const int l    = tid & 63;
    const int lr16 = l & 15;
    const int kq4  = l >> 4;

    const bfrag* W1c = (const bfrag*)W1p;
    const bfrag* W2c = (const bfrag*)W2p;
    const int wcb = wid * 64 + lr16;

    bfrag wb0[4], wb1[4];
    auto loadW = [&](int gs, bfrag* dst) {   // gs = global step 0..31
        const bfrag* Wc = (gs >= 16) ? W2c : W1c;
        const int base = ((gs & 15) * 4 + kq4) * 512 + wcb;
#pragma unroll
        for (int nt = 0; nt < 4; ++nt) dst[nt] = Wc[base + nt * 16];
    };

    loadW(0, wb0);

    // ---- E build: row = tid>>3 (64 rows), kc = tid&7 covers 64 k each ----
    {
        const int row = tid >> 3;
        const int kc  = tid & 7;
        const int b   = bc * 64 + row;
        const float* xi = (pi == Zi) ? (colp + b * Ff) : (nf + (b * Nn + pi) * Ff);
        const float* xj = (pj == Zi) ? (colp + b * Ff) : (nf + (b * Nn + pj) * Ff);
#pragma unroll
        for (int i = 0; i < 8; ++i) {
            const int k0 = kc * 64 + i * 8;
            const int plane = k0 >> 3;
            float4 u0 = *(const float4*)(xi + k0), u1 = *(const float4*)(xi + k0 + 4);
            float4 v0 = *(const float4*)(xj + k0), v1 = *(const float4*)(xj + k0 + 4);
            *(uint4*)(&Eb[(plane * PEC + row) * 16]) =
                pack8(u0.x*v0.x, u0.y*v0.y, u0.z*v0.z, u0.w*v0.w,
                      u1.x*v1.x, u1.y*v1.y, u1.z*v1.z, u1.w*v1.w);
        }
    }
    __syncthreads();    // E published

    f32x4 acc[4][4];
#pragma unroll
    for (int mt = 0; mt < 4; ++mt)
#pragma unroll
        for (int nt = 0; nt < 4; ++nt) acc[mt][nt] = (f32x4){0.f, 0.f, 0.f, 0.f};

#define DO_STEP(S, WB) { \
    const int ebase = ((S) & 15) * 4 + kq4; \
    bfrag a0 = *(const bfrag*)(&Eb[(ebase * PEC +      lr16) * 16]); \
    bfrag a1 = *(const bfrag*)(&Eb[(ebase * PEC + 16 + lr16) * 16]); \
    bfrag a2 = *(const bfrag*)(&Eb[(ebase * PEC + 32 + lr16) * 16]); \
    bfrag a3 = *(const bfrag*)(&Eb[(ebase * PEC + 48 + lr16) * 16]); \
    acc[0][0] = __builtin_amdgcn_mfma_f32_16x16x32_bf16(a0, WB[0], acc[0][0], 0, 0, 0); \
    acc[0][1] = __builtin_amdgcn_mfma_f32_16x16x32_bf16(a0, WB[1], acc[0][1], 0, 0, 0); \
    acc[0][2] = __builtin_amdgcn_mfma_f32_16x16x32_bf16(a0, WB[2], acc[0][2], 0, 0, 0); \
    acc[0][3] = __builtin_amdgcn_mfma_f32_16x16x32_bf16(a0, WB[3], acc[0][3], 0, 0, 0); \
    acc[1][0] = __builtin_amdgcn_mfma_f32_16x16x32_bf16(a1, WB[0], acc[1][0], 0, 0, 0); \
    acc[1][1] = __builtin_amdgcn_mfma_f32_16x16x32_bf16(a1, WB[1], acc[1][1], 0, 0, 0); \
    acc[1][2] = __builtin_amdgcn_mfma_f32_16x16x32_bf16(a1, WB[2], acc[1][2], 0, 0, 0); \
    acc[1][3] = __builtin_amdgcn_mfma_f32_16x16x32_bf16(a1, WB[3], acc[1][3], 0, 0, 0); \
    acc[2][0] = __builtin_amdgcn_mfma_f32_16x16x32_bf16(a2, WB[0], acc[2][0], 0, 0, 0); \
    acc[2][1] = __builtin_amdgcn_mfma_f32_16x16x32_bf16(a2, WB[1], acc[2][1], 0, 0, 0); \
    acc[2][2] = __builtin_amdgcn_mfma_f32_16x16x32_bf16(a2, WB[2], acc[2][2], 0, 0, 0); \
    acc[2][3] = __builtin_amdgcn_mfma_f32_16x16x32_bf16(a2, WB[3], acc[2][3], 0, 0, 0); \
    acc[3][0] = __builtin_amdgcn_mfma_f32_16x16x32_bf16(a3, WB[0], acc[3][0], 0, 0, 0); \
    acc[3][1] = __builtin_amdgcn_mfma_f32_16x16x32_bf16(a3, WB[1], acc[3][1], 0, 0, 0); \
    acc[3][2] = __builtin_amdgcn_mfma_f32_16x16x32_bf16(a3, WB[2], acc[3][2], 0, 0, 0); \
    acc[3][3] = __builtin_amdgcn_mfma_f32_16x16x32_bf16(a3, WB[3], acc[3][3], 0, 0, 0); }

    // ---- layer 1: steps 0..15 (no barriers) ----
#pragma unroll 1
    for (int s2 = 0; s2 < 8; ++s2) {
        const int s = 2 * s2;
        loadW(s + 1, wb1);
        DO_STEP(s, wb0)
        loadW(s + 2, wb0);           // s2==7 -> slice 16 = W2 slice 0
        DO_STEP(s + 1, wb1)
    }

    // ---- layer boundary: h1 = relu(acc+b1) -> Eb in place ----
    __syncthreads();                 // all layer-1 E reads done
    {
#pragma unroll
        for (int nt = 0; nt < 4; ++nt) {
            const int c  = wid * 64 + nt * 16 + lr16;
            const float bv = b1[c];
#pragma unroll
            for (int mt = 0; mt < 4; ++mt)
#pragma unroll
                for (int reg = 0; reg < 4; ++reg) {
                    int row = mt * 16 + kq4 * 4 + reg;
                    float v = fmaxf(acc[mt][nt][reg] + bv, 0.f);
                    *(unsigned short*)(&Eb[((c >> 3) * PEC + row) * 16 + (c & 7) * 2]) =
                        (unsigned short)f2bf(v);
                }
        }
#pragma unroll
        for (int mt = 0; mt < 4; ++mt)
#pragma unroll
            for (int nt = 0; nt < 4; ++nt) acc[mt][nt] = (f32x4){0.f, 0.f, 0.f, 0.f};
    }
    __syncthreads();                 // h1 published

    // ---- layer 2: steps 16..31 (no barriers) ----
#pragma unroll 1
    for (int s2 = 0; s2 < 8; ++s2) {
        const int s = 16 + 2 * s2;
        loadW(s + 1, wb1);
        DO_STEP(s, wb0)
        if (s2 < 7) loadW(s + 2, wb0);
        DO_STEP(s + 1, wb1)
    }
#undef DO_STEP

    // ---- fused layer-3: rowsum of relu(acc+b2)*w_out ----
    {
        float rs[4][4];
#pragma unroll
        for (int mt = 0; mt < 4; ++mt)
#pragma unroll
            for (int reg = 0; reg < 4; ++reg) rs[mt][reg] = 0.f;
#pragma unroll
        for (int nt = 0; nt < 4; ++nt) {
            const int c  = wid * 64 + nt * 16 + lr16;
            const float bv = b2[c];
            const float wv = w_out[c];
#pragma unroll
            for (int mt = 0; mt < 4; ++mt)
#pragma unroll
                for (int reg = 0; reg < 4; ++reg)
                    rs[mt][reg] += fmaxf(acc[mt][nt][reg] + bv, 0.f) * wv;
        }
#pragma unroll
        for (int off = 1; off < 16; off <<= 1)
#pragma unroll
            for (int mt = 0; mt < 4; ++mt)
#pragma unroll
                for (int reg = 0; reg < 4; ++reg)
                    rs[mt][reg] += __shfl_xor(rs[mt][reg], off);
        if (lr16 == 0) {
#pragma unroll
            for (int mt = 0; mt < 4; ++mt)
#pragma unroll
                for (int reg = 0; reg < 4; ++reg) {
                    int row = mt * 16 + kq4 * 4 + reg;
                    Pl[wid][row] = rs[mt][reg];
                }
        }
    }
    __syncthreads();
    if (tid < 64) {
        float v = b_out[0];
#pragma unroll
        for (int w = 0; w < 8; ++w) v += Pl[w][tid];
        int b = bc * 64 + tid;
        adj[b * (Nn * Nn) + pi * Nn + pj] = v;
        if (pi != pj) adj[b * (Nn * Nn) + pj * Nn + pi] = v;
    }
}

// ---------------------------------------------------------------------------
// azmix: fused softmax(row Zi) + m_fix + m_zp-init.  grid Bsz*64/256.
// ---------------------------------------------------------------------------
__global__ void azmix_kernel(const float* __restrict__ adj, const float* __restrict__ nf,
                             const float* __restrict__ col,
                             float* __restrict__ a_z, float* __restrict__ m_fix,
                             unsigned short* __restrict__ m_zp) {
    int idx = blockIdx.x * 256 + threadIdx.x;   // Bsz*64
    int b = idx >> 6, kq = idx & 63;
    const float* row = adj + b * (Nn * Nn) + Zi * Nn;
    float az[Nn];
    {
        float mx = row[0];
#pragma unroll
        for (int j = 1; j < Nn; ++j) mx = fmaxf(mx, row[j]);
        float s = 0.f;
#pragma unroll
        for (int j = 0; j < Nn; ++j) { az[j] = expf(row[j] - mx); s += az[j]; }
        float inv = 1.f / s;
#pragma unroll
        for (int j = 0; j < Nn; ++j) az[j] *= inv;
    }
    if (kq < Nn) a_z[b * Nn + kq] = az[kq];

    const int f0 = kq * 8;
    float s0 = 0.f, s1 = 0.f, s2 = 0.f, s3 = 0.f, s4 = 0.f, s5 = 0.f, s6 = 0.f, s7 = 0.f;
#pragma unroll
    for (int j = 0; j < Nn - 1; ++j) {
        float aj = az[j];
        const float* p = nf + (b * Nn + j) * Ff + f0;
        float4 n0 = *(const float4*)p, n1 = *(const float4*)(p + 4);
        s0 += aj * n0.x; s1 += aj * n0.y; s2 += aj * n0.z; s3 += aj * n0.w;
        s4 += aj * n1.x; s5 += aj * n1.y; s6 += aj * n1.z; s7 += aj * n1.w;
    }
    *(float4*)(m_fix + b * Ff + f0)     = (float4){s0, s1, s2, s3};
    *(float4*)(m_fix + b * Ff + f0 + 4) = (float4){s4, s5, s6, s7};

    const float az10 = az[Zi];
    float4 c0 = *(const float4*)(col + b * Ff + f0);
    float4 c1 = *(const float4*)(col + b * Ff + f0 + 4);
    long long dc = (((long long)(b >> 6) * 64 + kq) << 6) + (b & 63);
    *(uint4*)((char*)m_zp + dc * 16) =
        pack8(s0 + az10*c0.x, s1 + az10*c0.y, s2 + az10*c0.z, s3 + az10*c0.w,
              s4 + az10*c1.x, s5 + az10*c1.y, s6 + az10*c1.z, s7 + az10*c1.w);
}

// ---------------------------------------------------------------------------
// gates: gi = m_z @ Wih^T ; gh = col @ Whh^T -> bf16 out.
// Block = 32 rows x 256 cols, 256 thr / 4 waves, wave tile 32x64 (acc[2][4]).
// A staged once via gl_lds (32 KB, lane-split plane pairs); W direct
// global->VGPR ping-pong. grid (12, 32): xb<6 -> gi, else gh. 4 blocks/CU.
// ---------------------------------------------------------------------------
__global__ __launch_bounds__(256, 4) void gates_kernel(
    const unsigned short* __restrict__ m_zp, const unsigned short* __restrict__ colbf,
    const unsigned short* __restrict__ Wihp, const unsigned short* __restrict__ Whhp,
    unsigned short* __restrict__ gi, unsigned short* __restrict__ gh)
{
    __shared__ __align__(16) char Ab[64 * 32 * 16];   // 32,768 B (plane stride 32)

    const int xb = blockIdx.x, bc = blockIdx.y, tid = threadIdx.x;
    const bool isGi = xb < 6;
    const int nbase = (isGi ? xb : xb - 6) * 256;
    const unsigned short* Ap = isGi ? m_zp : colbf;
    const unsigned short* Wp = isGi ? Wihp : Whhp;
    unsigned short* C = isGi ? gi : gh;

    const int wid  = tid >> 6;
    const int l    = tid & 63;
    const int lr16 = l & 15;
    const int kq4  = l >> 4;

    const bfrag* Wc = (const bfrag*)Wp;
    const int wcb = ((nbase >> 9) << 15) + (nbase & 511) + wid * 64 + lr16;

    bfrag wb0[4], wb1[4];
    auto loadW = [&](int s, bfrag* dst) {   // s = step 0..15
        if (s > 15) s = 15;
        const int base = wcb + (s * 4 + kq4) * 512;
#pragma unroll
        for (int nt = 0; nt < 4; ++nt) dst[nt] = Wc[base + nt * 16];
    };

    loadW(0, wb0);

    // ---- stage A (32 KB; each gl_lds covers plane pair 2j,2j+1: lane<32 ->
    // plane 2j row lane, lane>=32 -> plane 2j+1 row lane-32; dest linear) ----
    {
        const long long gbase = (long long)(bc >> 1) * 4096 + (bc & 1) * 32 + (l & 31);
#pragma unroll
        for (int i = 0; i < 8; ++i) {
            const int j = i * 4 + wid;                 // plane pair index 0..31
            const int plane = 2 * j + (l >> 5);
            gl_lds16(Ap + (gbase + (long long)plane * 64) * 8,
                     (char*)Ab + j * 1024);
        }
    }
    __syncthreads();   // drains gl_lds + W slice 0

    f32x4 acc[2][4];
#pragma unroll
    for (int mt = 0; mt < 2; ++mt)
#pragma unroll
        for (int nt = 0; nt < 4; ++nt) acc[mt][nt] = (f32x4){0.f, 0.f, 0.f, 0.f};

#define DO_STEPG(S, WB) { \
    const int ebase = (S) * 4 + kq4; \
    bfrag a0 = *(const bfrag*)(&Ab[(ebase * 32 +      lr16) * 16]); \
    bfrag a1 = *(const bfrag*)(&Ab[(ebase * 32 + 16 + lr16) * 16]); \
    acc[0][0] = __builtin_amdgcn_mfma_f32_16x16x32_bf16(a0, WB[0], acc[0][0], 0, 0, 0); \
    acc[0][1] = __builtin_amdgcn_mfma_f32_16x16x32_bf16(a0, WB[1], acc[0][1], 0, 0, 0); \
    acc[0][2] = __builtin_amdgcn_mfma_f32_16x16x32_bf16(a0, WB[2], acc[0][2], 0, 0, 0); \
    acc[0][3] = __builtin_amdgcn_mfma_f32_16x16x32_bf16(a0, WB[3], acc[0][3], 0, 0, 0); \
    acc[1][0] = __builtin_amdgcn_mfma_f32_16x16x32_bf16(a1, WB[0], acc[1][0], 0, 0, 0); \
    acc[1][1] = __builtin_amdgcn_mfma_f32_16x16x32_bf16(a1, WB[1], acc[1][1], 0, 0, 0); \
    acc[1][2] = __builtin_amdgcn_mfma_f32_16x16x32_bf16(a1, WB[2], acc[1][2], 0, 0, 0); \
    acc[1][3] = __builtin_amdgcn_mfma_f32_16x16x32_bf16(a1, WB[3], acc[1][3], 0, 0, 0); }

#pragma unroll 1
    for (int s2 = 0; s2 < 8; ++s2) {
        const int s = 2 * s2;
        loadW(s + 1, wb1);
        DO_STEPG(s, wb0)
        if (s2 < 7) loadW(s + 2, wb0);
        DO_STEPG(s + 1, wb1)
    }
#undef DO_STEPG

    // ---- epilogue: bf16 stores ----
#pragma unroll
    for (int nt = 0; nt < 4; ++nt) {
        const int c = nbase + wid * 64 + nt * 16 + lr16;
#pragma unroll
        for (int mt = 0; mt < 2; ++mt)
#pragma unroll
            for (int reg = 0; reg < 4; ++reg) {
                int row = mt * 16 + kq4 * 4 + reg;
                C[(long long)(bc * 32 + row) * G3 + c] = (unsigned short)f2bf(acc[mt][nt][reg]);
            }
    }
}

// ---------------------------------------------------------------------------
// gru3: GRU pointwise (bf16 gate inputs) + fused colbf AND next-step m_zp.
// ---------------------------------------------------------------------------
__global__ void gru3_kernel(const unsigned short* __restrict__ gi,
                            const unsigned short* __restrict__ gh,
                            const float* __restrict__ m_fix, const float* __restrict__ a_z,
                            float* __restrict__ col,
                            unsigned short* __restrict__ colbf,
                            unsigned short* __restrict__ m_zp) {
    int idx = blockIdx.x * 256 + threadIdx.x;   // Bsz*64
    int b = idx >> 6, kq = idx & 63;
    const int f0 = kq * 8;
    const unsigned short* gib = gi + (long long)b * G3;
    const unsigned short* ghb = gh + (long long)b * G3;

    uint4 irp = *(const uint4*)(gib + f0);
    uint4 izp = *(const uint4*)(gib + 512 + f0);
    uint4 inp = *(const uint4*)(gib + 1024 + f0);
    uint4 hrp = *(const uint4*)(ghb + f0);
    uint4 hzp = *(const uint4*)(ghb + 512 + f0);
    uint4 hnp = *(const uint4*)(ghb + 1024 + f0);
    float4 h0 = *(const float4*)(col + b * Ff + f0);
    float4 h1 = *(const float4*)(col + b * Ff + f0 + 4);
    float hv[8] = {h0.x, h0.y, h0.z, h0.w, h1.x, h1.y, h1.z, h1.w};

    const unsigned* irw = (const unsigned*)&irp;
    const unsigned* izw = (const unsigned*)&izp;
    const unsigned* inw = (const unsigned*)&inp;
    const unsigned* hrw = (const unsigned*)&hrp;
    const unsigned* hzw = (const unsigned*)&hzp;
    const unsigned* hnw = (const unsigned*)&hnp;

    float o[8];
#pragma unroll
    for (int k = 0; k < 8; ++k) {
        const int w = k >> 1, hi = k & 1;
        float ir = bf2f((unsigned short)(irw[w] >> (hi * 16)));
        float iz = bf2f((unsigned short)(izw[w] >> (hi * 16)));
        float in = bf2f((unsigned short)(inw[w] >> (hi * 16)));
        float hr = bf2f((unsigned short)(hrw[w] >> (hi * 16)));
        float hz = bf2f((unsigned short)(hzw[w] >> (hi * 16)));
        float hn = bf2f((unsigned short)(hnw[w] >> (hi * 16)));
        float r = 1.f / (1.f + expf(-(ir + hr)));
        float z = 1.f / (1.f + expf(-(iz + hz)));
        float n = tanhf(in + r * hn);
        o[k] = (1.f - z) * n + z * hv[k];
    }

    *(float4*)(col + b * Ff + f0)     = (float4){o[0], o[1], o[2], o[3]};
    *(float4*)(col + b * Ff + f0 + 4) = (float4){o[4], o[5], o[6], o[7]};
    long long dc = (((long long)(b >> 6) * 64 + kq) << 6) + (b & 63);
    *(uint4*)((char*)colbf + dc * 16) = pack8(o[0], o[1], o[2], o[3], o[4], o[5], o[6], o[7]);

    const float az10 = a_z[b * Nn + Zi];
    float4 m0 = *(const float4*)(m_fix + b * Ff + f0);
    float4 m1 = *(const float4*)(m_fix + b * Ff + f0 + 4);
    *(uint4*)((char*)m_zp + dc * 16) =
        pack8(m0.x + az10*o[0], m0.y + az10*o[1], m0.z + az10*o[2], m0.w + az10*o[3],
              m1.x + az10*o[4], m1.y + az10*o[5], m1.z + az10*o[6], m1.w + az10*o[7]);
}

// ---------------------------------------------------------------------------
extern "C" void kernel_launch(void* const* d_in, const int* in_sizes, int n_in,
                              void* d_out, int out_size, void* d_ws, size_t ws_size,
                              hipStream_t stream) {
    const float* nf    = (const float*)d_in[0];
    const float* W1    = (const float*)d_in[1];
    const float* b1    = (const float*)d_in[2];
    const float* W2    = (const float*)d_in[3];
    const float* b2    = (const float*)d_in[4];
    const float* w_out = (const float*)d_in[5];
    const float* b_out = (const float*)d_in[6];
    const float* W_ih  = (const float*)d_in[7];
    const float* W_hh  = (const float*)d_in[8];

    float* adj = (float*)d_out;                 // (B, 11, 11)
    float* col = adj + Bsz * Nn * Nn;           // (B, 512)

    unsigned short* W1p   = (unsigned short*)d_ws;       // packed, 512x512
    unsigned short* W2p   = W1p + Ff * Ff;
    unsigned short* Wihp  = W2p + Ff * Ff;               // packed, 1536x512
    unsigned short* Whhp  = Wihp + G3 * Ff;
    float* a_z            = (float*)(Whhp + G3 * Ff);    // 16384 floats
    float* m_fix          = a_z + 16384;                 // B*512 fp32
    unsigned short* m_zp  = (unsigned short*)(m_fix + Bsz * Ff);  // B*512 packed
    unsigned short* colbf = m_zp + Bsz * Ff;                      // B*512 packed
    unsigned short* gi    = colbf + Bsz * Ff;            // B*1536 bf16
    unsigned short* gh    = gi + (long long)Bsz * G3;    // B*1536 bf16

    init_col2_kernel<<<(Bsz * 64) / 256, 256, 0, stream>>>(nf, col, colbf);
    pack_w_kernel<<<(Ff * 64) / 256, 256, 0, stream>>>(W1, W1p, 9);
    pack_w_kernel<<<(Ff * 64) / 256, 256, 0, stream>>>(W2, W2p, 9);
    pack_w_kernel<<<(G3 * 64) / 256, 256, 0, stream>>>(W_ih, Wihp, 9);
    pack_w_kernel<<<(G3 * 64) / 256, 256, 0, stream>>>(W_hh, Whhp, 9);

    for (int t = 0; t < 3; ++t) {
        const int mode   = (t == 0) ? 0 : 1;
        const int npairs = (t == 0) ? 66 : 11;

        link_kernel<<<npairs * 16, 512, 0, stream>>>(nf, col, W1p, b1, W2p, b2,
                                                     w_out, b_out, adj, mode);
        azmix_kernel<<<(Bsz * 64) / 256, 256, 0, stream>>>(adj, nf, col, a_z, m_fix, m_zp);

        for (int s = 0; s < 3; ++s) {
            gates_kernel<<<dim3(12, 32), 256, 0, stream>>>(m_zp, colbf, Wihp, Whhp, gi, gh);
            gru3_kernel<<<(Bsz * 64) / 256, 256, 0, stream>>>(gi, gh, m_fix, a_z,
                                                              col, colbf, m_zp);
        }
    }
}